// Round 8
// baseline (1144.612 us; speedup 1.0000x reference)
//
#include <hip/hip_runtime.h>
#include <cmath>
#include <cstdint>
#include <cstddef>

typedef unsigned int u32;
typedef unsigned short u16;
typedef unsigned long long u64;
typedef __attribute__((ext_vector_type(8))) short short8v;
typedef __attribute__((ext_vector_type(4))) float f32x4;

#define TPB 256
#define EPSV 1e-5f
#define SLP 0.2f

__device__ __forceinline__ float lrelu(float x){ return x >= 0.f ? x : SLP*x; }
__device__ __forceinline__ u32 encf(float f){ u32 u=__float_as_uint(f); return (u&0x80000000u)? ~u : (u|0x80000000u); }
__device__ __forceinline__ float decf(u32 e){ return (e&0x80000000u)? __uint_as_float(e&0x7FFFFFFFu) : __uint_as_float(~e); }
__device__ __forceinline__ u16 f2b(float f){ u32 u=__float_as_uint(f); return (u16)((u + 0x7FFFu + ((u>>16)&1u))>>16); }
__device__ __forceinline__ float b2f(u16 h){ return __uint_as_float(((u32)h)<<16); }

// ---- dtype detector ----
__global__ void k_detect(const u16* __restrict__ raw, int n, int* __restrict__ flag){
  __shared__ float red[TPB];
  int tid=threadIdx.x; float m=0.f;
  for(int i=tid;i<n;i+=TPB){
    float v=fabsf(b2f(raw[i]));
    if(!isnan(v) && !isinf(v) && v>m) m=v;
  }
  red[tid]=m; __syncthreads();
  for(int s=TPB/2;s>0;s>>=1){ if(tid<s) red[tid]=fmaxf(red[tid],red[tid+s]); __syncthreads(); }
  if(tid==0) *flag = (red[0] > 1000.f) ? 1 : 0;
}

// ---- all-inputs -> f32 ----
struct CvtArgs{ const void* s[18]; float* d[18]; int n[18]; };
__global__ void k_cvt_all(CvtArgs a, const int* __restrict__ flag){
  int z=blockIdx.y; int n=a.n[z]; int f=*flag;
  const void* s=a.s[z]; float* d=a.d[z];
  for(int i=blockIdx.x*TPB+threadIdx.x; i<n; i+=gridDim.x*TPB)
    d[i] = f ? ((const float*)s)[i] : b2f(((const u16*)s)[i]);
}

// ---- f32 -> bf16 cast (weights) ----
__global__ void k_castw(const float* __restrict__ W, u16* __restrict__ Wb, int n){
  int i=blockIdx.x*TPB+threadIdx.x; if(i<n) Wb[i]=f2b(W[i]);
}

// ---- transpose+cast: X [b][c][N](ldC rows used C) -> bf16 [b][n][C] ----
__global__ void k_xpose_bf(const float* __restrict__ X, u16* __restrict__ Xb,
                           int ldC, int C, int N){
  __shared__ float t[32][33];
  int b=blockIdx.z;
  int c0=blockIdx.y*32, n0=blockIdx.x*32;
  int tx=threadIdx.x&31, ty=threadIdx.x>>5;
  const float* Xs = X + (size_t)b*ldC*N;
  #pragma unroll
  for(int i=0;i<4;i++){
    int c=c0+ty+i*8;
    t[ty+i*8][tx] = (c<C && n0+tx<N) ? Xs[(size_t)c*N + n0+tx] : 0.f;
  }
  __syncthreads();
  u16* Ob = Xb + (size_t)b*N*C;
  #pragma unroll
  for(int i=0;i<4;i++){
    int n=n0+ty+i*8;
    if(n<N && c0+tx<C) Ob[(size_t)n*C + c0+tx] = f2b(t[tx][ty+i*8]);
  }
}

// ---- MFMA convmax (gseg only, no bias) ----
template<int KSTEPS>
__global__ __launch_bounds__(256) void k_convmax_mfma(
    const u16* __restrict__ Wb, const u16* __restrict__ Xb,
    u32* __restrict__ gmaxEnc, int gstride, int g_off, double* __restrict__ stats,
    int C, int N, int O){
  int tid=threadIdx.x, lane=tid&63, w=tid>>6;
  int b=blockIdx.z;
  int oW = blockIdx.y*64 + w*16;
  int nB = blockIdx.x*256;
  int row16 = lane&15, grp = lane>>4;
  short8v af[KSTEPS];
  const u16* Wrow = Wb + (size_t)(oW + row16)*C + grp*8;
  #pragma unroll
  for(int ks=0;ks<KSTEPS;ks++) af[ks] = *(const short8v*)(Wrow + ks*32);
  const short8v zb = {0,0,0,0,0,0,0,0};
  f32x4 acc[16];
  #pragma unroll
  for(int t=0;t<16;t++){
    int n = nB + t*16 + row16;
    bool nv = (n < N);
    const u16* Xrow = Xb + ((size_t)b*N + (nv? n:0))*C + grp*8;
    short8v bf[KSTEPS];
    #pragma unroll
    for(int ks=0;ks<KSTEPS;ks++) bf[ks] = nv ? *(const short8v*)(Xrow + ks*32) : zb;
    f32x4 a = {0.f,0.f,0.f,0.f};
    #pragma unroll
    for(int ks=0;ks<KSTEPS;ks++)
      a = __builtin_amdgcn_mfma_f32_16x16x32_bf16(af[ks], bf[ks], a, 0, 0, 0);
    acc[t]=a;
  }
  float mxr[4], s1r[4], s2r[4];
  #pragma unroll
  for(int r=0;r<4;r++){ mxr[r]=-INFINITY; s1r[r]=0.f; s2r[r]=0.f; }
  #pragma unroll
  for(int t=0;t<16;t++){
    int n = nB + t*16 + row16;
    bool nv = (n<N);
    #pragma unroll
    for(int r=0;r<4;r++){
      float y = acc[t][r];
      if(nv){ mxr[r]=fmaxf(mxr[r],y); s1r[r]+=y; s2r[r]+=y*y; }
    }
  }
  #pragma unroll
  for(int s=1;s<16;s<<=1){
    #pragma unroll
    for(int r=0;r<4;r++){
      mxr[r]=fmaxf(mxr[r], __shfl_xor(mxr[r], s));
      s1r[r]+=__shfl_xor(s1r[r], s);
      s2r[r]+=__shfl_xor(s2r[r], s);
    }
  }
  if(row16==0){
    #pragma unroll
    for(int r=0;r<4;r++){
      int o = oW + grp*4 + r;
      atomicMax(&gmaxEnc[(size_t)b*gstride + g_off + o], encf(mxr[r]));
      atomicAdd(&stats[2*o], (double)s1r[r]);
      atomicAdd(&stats[2*o+1], (double)s2r[r]);
    }
  }
}

// ---- squared norms ----
__global__ void k_sqnorm(const float* __restrict__ X, float* __restrict__ xx, int B, int ldC, int C, int N){
  int i=blockIdx.x*TPB+threadIdx.x; if(i>=B*N) return;
  int b=i/N, n=i-b*N;
  const float* p = X + ((size_t)b*ldC)*N + n;
  float s=0.f;
  for(int c=0;c<C;c++){ float x=p[(size_t)c*N]; s+=x*x; }
  xx[i]=s;
}

// ---- FUSED kNN: XCD swizzle (r7, FETCH 8.2x reduction verified) +
// half-split stripe (16KB dynamic + 4KB cand = 20KB -> 8 blocks/CU).
// Pass h computes columns [h*1024, (h+1)*1024) with identical per-column
// c-accumulation order; selection byte-identical -> bit-identical results.
template<int JMAX, int CT>
__global__ __launch_bounds__(256, 6) void k_knn_fused(
    const float* __restrict__ X, const float* __restrict__ xx,
    int ldC, int KSEL, int* __restrict__ idxOut){
  const int N = JMAX*64;
  extern __shared__ float sm[];              // JMAX==32: [4][1024], else [4][N]
  __shared__ u64 cand[4][128];
  int tid=threadIdx.x, lane=tid&63, w=tid>>6;
  int b, row0;
  if constexpr (JMAX==32){
    int lin=blockIdx.x, xcd=lin&7, j=lin>>3;
    b = xcd + ((j>>9)<<3);
    row0 = (j&511)*4;
  } else {
    b = blockIdx.y; row0 = blockIdx.x*4;
  }
  const float* Xb = X + (size_t)b*ldC*N;
  const float* xxb = xx + (size_t)b*N;

  u32 ev[JMAX];

  // ---- compute phase ----
  if constexpr (JMAX==32){
    int c0 = tid*4;
    #pragma unroll
    for(int h=0;h<2;h++){
      float4 acc0[4];
      #pragma unroll
      for(int r=0;r<4;r++) acc0[r]=make_float4(0,0,0,0);
      #pragma unroll 4
      for(int c=0;c<CT;c++){
        const float* Xc = Xb + (size_t)c*N;
        float4 b0 = *(const float4*)&Xc[h*1024 + c0];
        #pragma unroll
        for(int r=0;r<4;r++){
          float a = Xc[row0+r];
          acc0[r].x += a*b0.x; acc0[r].y += a*b0.y; acc0[r].z += a*b0.z; acc0[r].w += a*b0.w;
        }
      }
      float4 xm0 = *(const float4*)&xxb[h*1024 + c0];
      #pragma unroll
      for(int r=0;r<4;r++){
        float xr = xxb[row0+r];
        float4 d0;
        d0.x=2.f*acc0[r].x-xr-xm0.x; d0.y=2.f*acc0[r].y-xr-xm0.y;
        d0.z=2.f*acc0[r].z-xr-xm0.z; d0.w=2.f*acc0[r].w-xr-xm0.w;
        *(float4*)&sm[r*1024 + c0] = d0;
      }
      __syncthreads();
      const float* Sr = sm + (size_t)w*1024;
      #pragma unroll
      for(int ch=0;ch<4;ch++){
        float4 v = *(const float4*)&Sr[ch*256 + lane*4];
        int base = h*16 + ch*4;
        ev[base+0]=encf(v.x); ev[base+1]=encf(v.y);
        ev[base+2]=encf(v.z); ev[base+3]=encf(v.w);
      }
      if(h==0) __syncthreads();   // stripe overwritten by pass 2
    }
  } else {
    int tcol = (tid < N)? tid : (tid & (N-1));
    float acc[4];
    #pragma unroll
    for(int r=0;r<4;r++) acc[r]=0.f;
    #pragma unroll 4
    for(int c=0;c<CT;c++){
      const float* Xc = Xb + (size_t)c*N;
      float bv = Xc[tcol];
      #pragma unroll
      for(int r=0;r<4;r++) acc[r] += Xc[row0+r]*bv;
    }
    float xm = xxb[tcol];
    #pragma unroll
    for(int r=0;r<4;r++) sm[r*N + tcol] = 2.f*acc[r] - xxb[row0+r] - xm;
    __syncthreads();
    const float* Sr = sm + (size_t)w*N;
    if constexpr (JMAX>=4){
      #pragma unroll
      for(int ch=0;ch<JMAX/4;ch++){
        float4 v = *(const float4*)&Sr[ch*256 + lane*4];
        ev[ch*4+0]=encf(v.x); ev[ch*4+1]=encf(v.y); ev[ch*4+2]=encf(v.z); ev[ch*4+3]=encf(v.w);
      }
    } else {
      ev[0]=encf(Sr[lane]);
    }
  }

  // ---- selection phase: wave w handles row w (byte-identical to r0) ----
  u64* cw = cand[w];
  int* op = idxOut + ((size_t)b*N + row0 + w)*KSEL;
  if constexpr (JMAX>=8){
    u32 vmax=ev[0];
    #pragma unroll
    for(int j=1;j<JMAX;j++) vmax = vmax>ev[j]? vmax:ev[j];
    u32 lo=0u, hi=0xFFFFFFFFu;
    while(lo<hi){
      u32 d=hi-lo; u32 mid=lo+(d>>1)+(d&1u);
      int cnum=(int)__popcll(__ballot(vmax>=mid));
      if(cnum>=KSEL) lo=mid; else hi=mid-1u;
    }
    u32 T=lo;
    u64 lml=((u64)1<<lane)-1ull;
    u32 base=0;
    #pragma unroll
    for(int j=0;j<JMAX;j++){
      bool p = ev[j]>=T;
      u64 mk=__ballot(p);
      u32 pos=base+(u32)__popcll(mk&lml);
      int m = (j>>2)*256 + lane*4 + (j&3);
      if(p && pos<128u) cw[pos] = ((u64)ev[j]<<32) | (u64)(u32)(~(u32)m);
      base += (u32)__popcll(mk);
    }
    int nc=(int)base;
    if(nc<=64){
      u64 cv = cw[lane];
      if(lane>=nc) cv=0ull;
      #pragma unroll
      for(int kk=2;kk<=64;kk<<=1){
        #pragma unroll
        for(int jj=kk>>1;jj>0;jj>>=1){
          u64 p=__shfl_xor(cv,jj);
          bool takeMax=(((lane&jj)!=0)==((lane&kk)==0));
          u64 mx=cv>p?cv:p, mn=cv>p?p:cv;
          cv=takeMax?mx:mn;
        }
      }
      if(lane>=64-KSEL) op[63-lane]=(int)(~(u32)cv);
    } else if(nc<=128){
      u64 c0v=cw[lane], c1v=cw[64+lane];
      if(64+lane>=nc) c1v=0ull;
      u64 kl=~0ull;
      for(int t=0;t<KSEL;t++){
        u64 bk=(c0v<kl)?c0v:0ull;
        if(c1v<kl&&c1v>bk) bk=c1v;
        #pragma unroll
        for(int s=1;s<64;s<<=1){u64 ok=__shfl_xor(bk,s); if(ok>bk)bk=ok;}
        if(lane==0) op[t]=(int)(~(u32)bk);
        kl=bk;
      }
    } else {
      u64 kl=~0ull;
      for(int t=0;t<KSEL;t++){
        u64 bk=0ull;
        #pragma unroll
        for(int j=0;j<JMAX;j++){
          int m = (j>>2)*256 + lane*4 + (j&3);
          u64 kj=((u64)ev[j]<<32)|(u64)(u32)(~(u32)m);
          if(kj<kl&&kj>bk) bk=kj;
        }
        #pragma unroll
        for(int s=1;s<64;s<<=1){u64 ok=__shfl_xor(bk,s); if(ok>bk)bk=ok;}
        if(lane==0) op[t]=(int)(~(u32)bk);
        kl=bk;
      }
    }
  } else {
    u64 key[JMAX];
    #pragma unroll
    for(int j=0;j<JMAX;j++){
      int m = (JMAX>=4)? ((j>>2)*256 + lane*4 + (j&3)) : lane;
      key[j]=((u64)ev[j]<<32)|(u64)(u32)(~(u32)m);
    }
    u64 kl=~0ull;
    for(int t=0;t<KSEL;t++){
      u64 bk=0ull;
      #pragma unroll
      for(int j=0;j<JMAX;j++){ u64 kj=key[j]; if(kj<kl&&kj>bk) bk=kj; }
      #pragma unroll
      for(int s=1;s<64;s<<=1){u64 ok=__shfl_xor(bk,s); if(ok>bk)bk=ok;}
      if(lane==0) op[t]=(int)(~(u32)bk);
      kl=bk;
    }
  }
}

// ---- full bitonic sort top-K for pools ----
__global__ void k_topk_sort(const float* __restrict__ S, int M, int K,
                            int* __restrict__ idxOut, float* __restrict__ valOut){
  extern __shared__ u64 key[];
  int b=blockIdx.x, tid=threadIdx.x;
  const float* Sr = S + (size_t)b*M;
  for(int i=tid;i<M;i+=TPB)
    key[i] = ((u64)(~encf(Sr[i]))<<32) | (u32)i;
  __syncthreads();
  for(int k=2;k<=M;k<<=1){
    for(int j=k>>1;j>0;j>>=1){
      for(int i=tid;i<M;i+=TPB){
        int ixj=i^j;
        if(ixj>i){
          u64 a=key[i], c=key[ixj];
          bool up=((i&k)==0);
          if(up ? (a>c) : (a<c)){ key[i]=c; key[ixj]=a; }
        }
      }
      __syncthreads();
    }
  }
  for(int p=tid;p<K;p+=TPB){
    u64 kk=key[p];
    idxOut[(size_t)b*K+p]=(int)(u32)(kk&0xFFFFFFFFull);
    valOut[(size_t)b*K+p]=decf(~(u32)(kk>>32));
  }
}

// ---- u = wA.x ; v = (wB-wA).x — 8-output tiled version. ----
__global__ __launch_bounds__(256) void k_uv_t(
    const float* __restrict__ X, int ldC, const float* __restrict__ W,
    float* __restrict__ U, float* __restrict__ V, int C, int N, int O){
  extern __shared__ float wsm[];             // [8][C][2]
  int tid=threadIdx.x, b=blockIdx.z;
  int o0=blockIdx.y*8;
  for(int i=tid;i<8*C;i+=TPB){
    int o=i/C, c=i-o*C;
    const float* Wr = W + (size_t)(o0+o)*2*C;
    float wa=Wr[c], wb=Wr[C+c];
    wsm[(size_t)(o*C+c)*2  ]=wa;
    wsm[(size_t)(o*C+c)*2+1]=wb-wa;
  }
  __syncthreads();
  int n=blockIdx.x*TPB+tid;
  bool act=(n<N); int nc=act? n:0;
  const float* Xb = X + ((size_t)b*ldC)*N + nc;
  float u[8], v[8];
  #pragma unroll
  for(int o=0;o<8;o++){ u[o]=0.f; v[o]=0.f; }
  for(int c=0;c<C;c++){
    float x = Xb[(size_t)c*N];
    #pragma unroll
    for(int o=0;o<8;o++){
      float2 wv = *(const float2*)&wsm[(size_t)(o*C+c)*2];
      u[o] += wv.x*x;
      v[o] += wv.y*x;
    }
  }
  if(act){
    #pragma unroll
    for(int o=0;o<8;o++){
      size_t off=((size_t)b*O+o0+o)*N+n;
      U[off]=u[o]; V[off]=v[o];
    }
  }
}

// ---- neighbor reduce ----
template<int KT, int OT>
__global__ void k_nbr_t(const float* __restrict__ U, const float* __restrict__ V, const int* __restrict__ idx,
                        float* __restrict__ outBase, int ldCout, int ch_off,
                        double* __restrict__ stats, int O, int N){
  __shared__ double redS[4][OT], redQ[4][OT];
  int tid=threadIdx.x, lane=tid&63, wv=tid>>6;
  int n = blockIdx.x*TPB+tid;
  int o0 = blockIdx.y*OT, b = blockIdx.z;
  bool act = (n<N);
  int nc = act? n : (N-1);
  int jr[KT];
  const int* jp = idx + ((size_t)b*N+nc)*KT;
  #pragma unroll
  for(int k=0;k<KT;k++){ int j=jp[k]; jr[k] = ((unsigned)j<(unsigned)N)? j : 0; }
  for(int oo=0;oo<OT;oo++){
    const float* Ur = U + ((size_t)b*O+o0+oo)*N;
    float mx=-INFINITY, s1=0.f, s2=0.f;
    #pragma unroll
    for(int k=0;k<KT;k++){ float u=Ur[jr[k]]; mx=fmaxf(mx,u); s1+=u; s2+=u*u; }
    float v = V[((size_t)b*O+o0+oo)*N+nc];
    if(act) outBase[((size_t)b*ldCout+ch_off+o0+oo)*N+n] = mx+v;
    double cs = act ? ((double)s1 + (double)KT*(double)v) : 0.0;
    double cq = act ? ((double)s2 + 2.0*(double)v*(double)s1 + (double)KT*(double)v*(double)v) : 0.0;
    #pragma unroll
    for(int s=1;s<64;s<<=1){ cs += __shfl_xor(cs,s); cq += __shfl_xor(cq,s); }
    if(lane==0){ redS[wv][oo]=cs; redQ[wv][oo]=cq; }
  }
  __syncthreads();
  if(tid<OT){
    double s=0,q=0;
    #pragma unroll
    for(int w=0;w<4;w++){ s+=redS[w][tid]; q+=redQ[w][tid]; }
    atomicAdd(&stats[2*(o0+tid)], s);
    atomicAdd(&stats[2*(o0+tid)+1], q);
  }
}

// ---- finalize BN + lrelu in place ----
__global__ void k_bnact(float* __restrict__ out, int ldCout, int ch_off, const double* __restrict__ stats,
                        int O, int N, double cnt){
  int n=blockIdx.x*TPB+threadIdx.x; if(n>=N) return;
  int o=blockIdx.y, b=blockIdx.z;
  double m=stats[2*o]/cnt;
  double var=stats[2*o+1]/cnt - m*m;
  float s=rsqrtf((float)var+EPSV);
  size_t p=((size_t)b*ldCout+ch_off+o)*N+n;
  float h=out[p];
  out[p] = lrelu((float)((double)h-m)*s);
}

// ---- f32 conv1 + max (+stats) — pools only ----
template<int PTS>
__global__ void k_convmax(const float* __restrict__ X, int ldC, const float* __restrict__ W, const float* __restrict__ bias,
                          u32* __restrict__ gmaxEnc, int gstride, int g_off, double* __restrict__ stats,
                          int C, int N, int O){
  __shared__ float red[4*16*3];
  int tid=threadIdx.x, ot=blockIdx.y, b=blockIdx.z;
  int lane=tid&63, wv=tid>>6;
  int n0 = blockIdx.x*TPB*PTS + tid*PTS;
  bool act = (n0 < N);
  int n0c = act ? n0 : (N-PTS);
  const float* Xb = X + ((size_t)b*ldC)*N;
  const float* Wr = W + (size_t)ot*16*C;
  float acc[16][PTS];
  #pragma unroll
  for(int oo=0;oo<16;oo++)
    #pragma unroll
    for(int p=0;p<PTS;p++) acc[oo][p]=0.f;
  for(int c=0;c<C;c+=4){
    float xv[4][PTS];
    #pragma unroll
    for(int cc=0;cc<4;cc++){
      if(PTS==4){
        float4 t = *(const float4*)&Xb[(size_t)(c+cc)*N + n0c];
        xv[cc][0]=t.x; xv[cc][1]=t.y; xv[cc][2]=t.z; xv[cc][3]=t.w;
      } else {
        xv[cc][0]=Xb[(size_t)(c+cc)*N + n0c];
      }
    }
    #pragma unroll
    for(int oo=0;oo<16;oo++){
      float w0=Wr[oo*C+c], w1=Wr[oo*C+c+1], w2=Wr[oo*C+c+2], w3=Wr[oo*C+c+3];
      #pragma unroll
      for(int p=0;p<PTS;p++)
        acc[oo][p] += w0*xv[0][p] + w1*xv[1][p] + w2*xv[2][p] + w3*xv[3][p];
    }
  }
  bool hs = (stats!=nullptr);
  #pragma unroll
  for(int oo=0;oo<16;oo++){
    float bval = bias? bias[ot*16+oo] : 0.f;
    float mx=-INFINITY, s1=0.f, s2=0.f;
    #pragma unroll
    for(int p=0;p<PTS;p++){
      float y=acc[oo][p]+bval;
      if(act && n0+p<N){ mx=fmaxf(mx,y); s1+=y; s2+=y*y; }
    }
    #pragma unroll
    for(int s=1;s<64;s<<=1){
      mx=fmaxf(mx,__shfl_xor(mx,s));
      if(hs){ s1+=__shfl_xor(s1,s); s2+=__shfl_xor(s2,s); }
    }
    if(lane==0){ red[(wv*16+oo)*3]=mx; red[(wv*16+oo)*3+1]=s1; red[(wv*16+oo)*3+2]=s2; }
  }
  __syncthreads();
  if(tid<16){
    int oo=tid, o=ot*16+oo;
    float mx=red[oo*3], s1=red[oo*3+1], s2=red[oo*3+2];
    #pragma unroll
    for(int w=1;w<4;w++){ mx=fmaxf(mx,red[(w*16+oo)*3]); s1+=red[(w*16+oo)*3+1]; s2+=red[(w*16+oo)*3+2]; }
    atomicMax(&gmaxEnc[(size_t)b*gstride+g_off+o], encf(mx));
    if(hs){ atomicAdd(&stats[2*o],(double)s1); atomicAdd(&stats[2*o+1],(double)s2); }
  }
}

// ---- g = lrelu(bn(max over n)) ----
__global__ void k_gfinal(const u32* __restrict__ gmaxEnc, int gstride, int g_off, const double* __restrict__ stats,
                         float* __restrict__ G, int B, int O, double cnt){
  int i=blockIdx.x*TPB+threadIdx.x; if(i>=B*O) return;
  int b=i/O, o=i-b*O;
  double m=stats[2*o]/cnt;
  double var=stats[2*o+1]/cnt - m*m;
  float s=rsqrtf((float)var+EPSV);
  float x=decf(gmaxEnc[(size_t)b*gstride+g_off+o]);
  G[(size_t)b*gstride+g_off+o]=lrelu((float)((double)x-m)*s);
}

// ---- pool attention scores ----
__global__ void k_scores(const float* __restrict__ X, int ldC, const u32* __restrict__ vecEnc,
                         float* __restrict__ sc, int C, int N){
  int n=blockIdx.x*TPB+threadIdx.x; if(n>=N) return;
  int b=blockIdx.y;
  const float* Xb = X + ((size_t)b*ldC)*N + n;
  double s=0;
  for(int c=0;c<C;c++) s += (double)Xb[(size_t)c*N]*(double)decf(vecEnc[(size_t)b*C+c]);
  float sf=(float)s;
  sc[(size_t)b*N+n]=1.f/(1.f+expf(-sf));
}

// ---- pool gather ----
__global__ void k_pgather(const float* __restrict__ xyz, int ldCx, const float* __restrict__ feat, int ldCf,
                          const int* __restrict__ pidx, const float* __restrict__ pval,
                          float* __restrict__ nodeOut, float* __restrict__ nfOut, int Cf, int Nin, int Kp){
  int b=blockIdx.y;
  int i=blockIdx.x*TPB+threadIdx.x;
  int total=(3+Cf)*Kp; if(i>=total) return;
  int c=i/Kp, p=i-c*Kp;
  int j=pidx[(size_t)b*Kp+p]; if((unsigned)j>=(unsigned)Nin) j=0;
  float v=pval[(size_t)b*Kp+p];
  if(c<3) nodeOut[((size_t)b*3+c)*Kp+p]=xyz[((size_t)b*ldCx+c)*Nin+j]*v;
  else { int cf=c-3; nfOut[((size_t)b*Cf+cf)*Kp+p]=feat[((size_t)b*ldCf+cf)*Nin+j]*v; }
}

// ---- fc: wave-per-output ----
__global__ void k_fc_wave(const float* __restrict__ A, const float* __restrict__ W, const float* __restrict__ bias,
                          float* __restrict__ Y, int B, int IN, int OUT){
  int gw = (blockIdx.x*blockDim.x + threadIdx.x) >> 6;
  if(gw >= B*OUT) return;
  int lane = threadIdx.x & 63;
  int b = gw/OUT, j = gw - b*OUT;
  const float4* a4 = (const float4*)(A + (size_t)b*IN);
  const float4* w4 = (const float4*)(W + (size_t)j*IN);
  int n4 = IN >> 2;
  float s = 0.f;
  for(int t=lane; t<n4; t+=64){
    float4 av=a4[t], wv=w4[t];
    s += av.x*wv.x + av.y*wv.y + av.z*wv.z + av.w*wv.w;
  }
  #pragma unroll
  for(int sh=1; sh<64; sh<<=1) s += __shfl_xor(s, sh);
  if(lane==0) Y[gw] = s + (bias? bias[j]:0.f);
}

// ---- BN over batch axis + lrelu ----
__global__ void k_bnb(const float* __restrict__ Y, float* __restrict__ H, int B, int F){
  int f=blockIdx.x*TPB+threadIdx.x; if(f>=F) return;
  double s=0,q=0;
  for(int b=0;b<B;b++){ double y=Y[(size_t)b*F+f]; s+=y; q+=y*y; }
  double m=s/B, var=q/B-m*m;
  float sc=rsqrtf((float)var+EPSV);
  for(int b=0;b<B;b++){ float y=Y[(size_t)b*F+f]; H[(size_t)b*F+f]=lrelu((float)((double)y-m)*sc); }
}

// ---- pack outputs ----
__global__ void k_out(const float* __restrict__ OUTF, const float* __restrict__ N1v, const float* __restrict__ N2v,
                      void* __restrict__ dout, const int* __restrict__ flag){
  int i=blockIdx.x*TPB+threadIdx.x; if(i>=16000) return;
  float v = (i<640)? OUTF[i] : (i<12928)? N1v[i-640] : N2v[i-12928];
  if(*flag) ((float*)dout)[i]=v; else ((u16*)dout)[i]=f2b(v);
}

extern "C" void kernel_launch(void* const* d_in, const int* in_sizes, int n_in,
                              void* d_out, int out_size, void* d_ws, size_t ws_size,
                              hipStream_t stream){
  const int B=16;
  char* basep=(char*)d_ws; size_t off=0;
  auto alloc=[&](size_t elems, size_t esz)->void*{
    off=(off+255)&~(size_t)255; void* p=basep+off; off+=elems*esz; return p;
  };
  const int NINP=18;
  const int insz[NINP]={98304,384,8192,131072,32768,32768,262144,131072,262144,16384,128,65536,256,1572864,131072,256,10240,40};
  float* F[NINP];
  for(int i=0;i<NINP;i++) F[i]=(float*)alloc((size_t)insz[i],4);
  float* XF=F[0];
  float *W1F=F[1],*W2F=F[2],*W2MF=F[3],*W3F=F[4],*W4F=F[5],*W4MF=F[6],*W5F=F[7],*W5MF=F[8],
        *WP1F=F[9],*BP1F=F[10],*WP2F=F[11],*BP2F=F[12],*WL1F=F[13],*WL2F=F[14],*BL2F=F[15],*WL3F=F[16],*BL3F=F[17];
  float* XX  =(float*)alloc((size_t)16*2048,4);
  float* U   =(float*)alloc((size_t)16*64*2048,4);
  float* V   =(float*)alloc((size_t)16*64*2048,4);
  float* XT1 =(float*)alloc((size_t)16*128*2048,4);
  float* XT2 =(float*)alloc((size_t)16*256*256,4);
  float* NF1 =(float*)alloc((size_t)16*128*256,4);
  float* NF2 =(float*)alloc((size_t)16*256*64,4);
  float* X5  =(float*)alloc((size_t)16*256*64,4);
  float* NODE1=(float*)alloc((size_t)16*3*256,4);
  float* NODE2=(float*)alloc((size_t)16*3*64,4);
  float* SCORES=(float*)alloc((size_t)16*2048,4);
  float* PVAL1=(float*)alloc((size_t)16*256,4);
  float* PVAL2=(float*)alloc((size_t)16*64,4);
  float* G   =(float*)alloc((size_t)16*3072,4);
  float* Y1  =(float*)alloc((size_t)16*512,4);
  float* H1  =(float*)alloc((size_t)16*512,4);
  float* Y2  =(float*)alloc((size_t)16*256,4);
  float* H2  =(float*)alloc((size_t)16*256,4);
  float* OUTF=(float*)alloc((size_t)16*40,4);
  u32* GMAX  =(u32*)alloc((size_t)16*3072,4);
  u32* VECENC=(u32*)alloc((size_t)16*256,4);
  int* IDX   =(int*)alloc((size_t)16*2048*20,4);
  int* PIDX1 =(int*)alloc((size_t)16*256,4);
  int* PIDX2 =(int*)alloc((size_t)16*64,4);
  double* STATS=(double*)alloc((size_t)2*1024,8);
  int* FLAG  =(int*)alloc(64,4);
  u16* XTB  =(u16*)alloc((size_t)16*2048*128,2);
  u16* WB2M =(u16*)alloc((size_t)131072,2);
  u16* WB4M =(u16*)alloc((size_t)262144,2);
  u16* WB5M =(u16*)alloc((size_t)262144,2);

  k_detect<<<dim3(1),dim3(TPB),0,stream>>>((const u16*)d_in[1], insz[1], FLAG);
  CvtArgs ca;
  for(int i=0;i<NINP;i++){ ca.s[i]=d_in[i]; ca.d[i]=F[i]; ca.n[i]=insz[i]; }
  k_cvt_all<<<dim3(64,NINP),dim3(TPB),0,stream>>>(ca, FLAG);
  k_castw<<<dim3((131072+TPB-1)/TPB),dim3(TPB),0,stream>>>(W2MF,WB2M,131072);
  k_castw<<<dim3((262144+TPB-1)/TPB),dim3(TPB),0,stream>>>(W4MF,WB4M,262144);
  k_castw<<<dim3((262144+TPB-1)/TPB),dim3(TPB),0,stream>>>(W5MF,WB5M,262144);

  auto knn=[&](const float* X, int ldC, int C, int N, int K){
    k_sqnorm<<<dim3((B*N+TPB-1)/TPB),dim3(TPB),0,stream>>>(X,XX,B,ldC,C,N);
    if(N==2048 && C==3)       k_knn_fused<32,3>  <<<dim3(8192),dim3(256),16384,stream>>>(X,XX,ldC,K,IDX);
    else if(N==2048)          k_knn_fused<32,64> <<<dim3(8192),dim3(256),16384,stream>>>(X,XX,ldC,K,IDX);
    else if(N==256)           k_knn_fused<4,128> <<<dim3(N/4,B),dim3(256),(size_t)4*N*4,stream>>>(X,XX,ldC,K,IDX);
    else                      k_knn_fused<1,256> <<<dim3(N/4,B),dim3(256),(size_t)4*N*4,stream>>>(X,XX,ldC,K,IDX);
  };

  auto graph_conv=[&](const float* X, int ldC, int C, int N, int K, const float* W, int O,
                      float* outBase, int ldCout, int ch_off){
    knn(X,ldC,C,N,K);
    size_t wshm=(size_t)8*C*2*4;
    k_uv_t<<<dim3((N+TPB-1)/TPB,O/8,B),dim3(TPB),wshm,stream>>>(X,ldC,W,U,V,C,N,O);
    hipMemsetAsync(STATS,0,2*(size_t)O*sizeof(double),stream);
    dim3 g((N+TPB-1)/TPB, O/8, B);
    if(K==20)      k_nbr_t<20,8><<<g,dim3(TPB),0,stream>>>(U,V,IDX,outBase,ldCout,ch_off,STATS,O,N);
    else if(K==10) k_nbr_t<10,8><<<g,dim3(TPB),0,stream>>>(U,V,IDX,outBase,ldCout,ch_off,STATS,O,N);
    else           k_nbr_t<5,8> <<<g,dim3(TPB),0,stream>>>(U,V,IDX,outBase,ldCout,ch_off,STATS,O,N);
    double cnt=(double)B*(double)N*(double)K;
    k_bnact<<<dim3((N+TPB-1)/TPB,O,B),dim3(TPB),0,stream>>>(outBase,ldCout,ch_off,STATS,O,N,cnt);
  };

  auto convmax_f32=[&](const float* X,int ldC,const float* W,const float* bias,
                   u32* gmax,int gstride,int g_off,double* stats,int C,int N,int O){
    if(N>=1024) k_convmax<4><<<dim3((N+TPB*4-1)/(TPB*4),O/16,B),dim3(TPB),0,stream>>>(X,ldC,W,bias,gmax,gstride,g_off,stats,C,N,O);
    else        k_convmax<1><<<dim3((N+TPB-1)/TPB,O/16,B),dim3(TPB),0,stream>>>(X,ldC,W,bias,gmax,gstride,g_off,stats,C,N,O);
  };

  auto pool=[&](const float* xyzF,int ldCx,const float* featF,int ldCf,int Cf,int Nin,
                const float* WP,const float* BP,int Op,int Kp,
                float* nodeOut,float* nfOut,int* pidx,float* pval){
    hipMemsetAsync(VECENC,0,(size_t)B*Op*4,stream);
    convmax_f32(featF,ldCf,WP,BP,VECENC,Op,0,(double*)nullptr,Cf,Nin,Op);
    k_scores<<<dim3((Nin+TPB-1)/TPB,B),dim3(TPB),0,stream>>>(featF,ldCf,VECENC,SCORES,Cf,Nin);
    k_topk_sort<<<dim3(B),dim3(TPB),(size_t)Nin*8,stream>>>(SCORES,Nin,Kp,pidx,pval);
    k_pgather<<<dim3(((3+Cf)*Kp+TPB-1)/TPB,B),dim3(TPB),0,stream>>>(xyzF,ldCx,featF,ldCf,pidx,pval,nodeOut,nfOut,Cf,Nin,Kp);
  };

  auto gseg=[&](const float* X,int ldC,int C,int N,const u16* WBc,int g_off,double cnt){
    hipMemsetAsync(STATS,0,2*1024*sizeof(double),stream);
    k_xpose_bf<<<dim3((N+31)/32,(C+31)/32,B),dim3(256),0,stream>>>(X,XTB,ldC,C,N);
    dim3 g((N+255)/256, 1024/64, B);
    if(C==128) k_convmax_mfma<4><<<g,dim3(256),0,stream>>>(WBc,XTB,GMAX,3072,g_off,STATS,C,N,1024);
    else       k_convmax_mfma<8><<<g,dim3(256),0,stream>>>(WBc,XTB,GMAX,3072,g_off,STATS,C,N,1024);
    k_gfinal<<<dim3((B*1024+TPB-1)/TPB),dim3(TPB),0,stream>>>(GMAX,3072,g_off,STATS,G,B,1024,cnt);
  };

  graph_conv(XF,3,3,2048,20,W1F,64,XT1,128,0);
  graph_conv(XT1,128,64,2048,20,W2F,64,XT1,128,64);
  hipMemsetAsync(GMAX,0,(size_t)16*3072*4,stream);
  gseg(XT1,128,128,2048,WB2M,0,(double)16*2048);
  pool(XF,3,XT1,128,128,2048,WP1F,BP1F,128,256,NODE1,NF1,PIDX1,PVAL1);
  graph_conv(NF1,128,128,256,10,W3F,128,XT2,256,0);
  graph_conv(XT2,256,128,256,10,W4F,128,XT2,256,128);
  gseg(XT2,256,256,256,WB4M,1024,(double)16*256);
  pool(NODE1,3,XT2,256,256,256,WP2F,BP2F,256,64,NODE2,NF2,PIDX2,PVAL2);
  graph_conv(NF2,256,256,64,5,W5F,256,X5,256,0);
  gseg(X5,256,256,64,WB5M,2048,(double)16*64);
  k_fc_wave<<<dim3((16*512*64+TPB-1)/TPB),dim3(TPB),0,stream>>>(G,WL1F,(const float*)nullptr,Y1,16,3072,512);
  k_bnb<<<dim3((512+TPB-1)/TPB),dim3(TPB),0,stream>>>(Y1,H1,16,512);
  k_fc_wave<<<dim3((16*256*64+TPB-1)/TPB),dim3(TPB),0,stream>>>(H1,WL2F,BL2F,Y2,16,512,256);
  k_bnb<<<dim3((256+TPB-1)/TPB),dim3(TPB),0,stream>>>(Y2,H2,16,256);
  k_fc_wave<<<dim3((16*40*64+TPB-1)/TPB),dim3(TPB),0,stream>>>(H2,WL3F,BL3F,OUTF,16,256,40);
  k_out<<<dim3((16000+TPB-1)/TPB),dim3(TPB),0,stream>>>(OUTF,NODE1,NODE2,(u16*)d_out,FLAG);
}

// Round 9
// 1086.741 us; speedup vs baseline: 1.0533x; 1.0533x over previous
//
#include <hip/hip_runtime.h>
#include <cmath>
#include <cstdint>
#include <cstddef>

typedef unsigned int u32;
typedef unsigned short u16;
typedef unsigned long long u64;
typedef __attribute__((ext_vector_type(8))) short short8v;
typedef __attribute__((ext_vector_type(4))) float f32x4;

#define TPB 256
#define EPSV 1e-5f
#define SLP 0.2f

__device__ __forceinline__ float lrelu(float x){ return x >= 0.f ? x : SLP*x; }
__device__ __forceinline__ u32 encf(float f){ u32 u=__float_as_uint(f); return (u&0x80000000u)? ~u : (u|0x80000000u); }
__device__ __forceinline__ float decf(u32 e){ return (e&0x80000000u)? __uint_as_float(e&0x7FFFFFFFu) : __uint_as_float(~e); }
__device__ __forceinline__ u16 f2b(float f){ u32 u=__float_as_uint(f); return (u16)((u + 0x7FFFu + ((u>>16)&1u))>>16); }
__device__ __forceinline__ float b2f(u16 h){ return __uint_as_float(((u32)h)<<16); }

// ---- dtype detector ----
__global__ void k_detect(const u16* __restrict__ raw, int n, int* __restrict__ flag){
  __shared__ float red[TPB];
  int tid=threadIdx.x; float m=0.f;
  for(int i=tid;i<n;i+=TPB){
    float v=fabsf(b2f(raw[i]));
    if(!isnan(v) && !isinf(v) && v>m) m=v;
  }
  red[tid]=m; __syncthreads();
  for(int s=TPB/2;s>0;s>>=1){ if(tid<s) red[tid]=fmaxf(red[tid],red[tid+s]); __syncthreads(); }
  if(tid==0) *flag = (red[0] > 1000.f) ? 1 : 0;
}

// ---- all-inputs -> f32 ----
struct CvtArgs{ const void* s[18]; float* d[18]; int n[18]; };
__global__ void k_cvt_all(CvtArgs a, const int* __restrict__ flag){
  int z=blockIdx.y; int n=a.n[z]; int f=*flag;
  const void* s=a.s[z]; float* d=a.d[z];
  for(int i=blockIdx.x*TPB+threadIdx.x; i<n; i+=gridDim.x*TPB)
    d[i] = f ? ((const float*)s)[i] : b2f(((const u16*)s)[i]);
}

// ---- f32 -> bf16 cast (weights) ----
__global__ void k_castw(const float* __restrict__ W, u16* __restrict__ Wb, int n){
  int i=blockIdx.x*TPB+threadIdx.x; if(i<n) Wb[i]=f2b(W[i]);
}

// ---- transpose+cast: X [b][c][N](ldC rows used C) -> bf16 [b][n][C] ----
__global__ void k_xpose_bf(const float* __restrict__ X, u16* __restrict__ Xb,
                           int ldC, int C, int N){
  __shared__ float t[32][33];
  int b=blockIdx.z;
  int c0=blockIdx.y*32, n0=blockIdx.x*32;
  int tx=threadIdx.x&31, ty=threadIdx.x>>5;
  const float* Xs = X + (size_t)b*ldC*N;
  #pragma unroll
  for(int i=0;i<4;i++){
    int c=c0+ty+i*8;
    t[ty+i*8][tx] = (c<C && n0+tx<N) ? Xs[(size_t)c*N + n0+tx] : 0.f;
  }
  __syncthreads();
  u16* Ob = Xb + (size_t)b*N*C;
  #pragma unroll
  for(int i=0;i<4;i++){
    int n=n0+ty+i*8;
    if(n<N && c0+tx<C) Ob[(size_t)n*C + c0+tx] = f2b(t[tx][ty+i*8]);
  }
}

// ---- MFMA convmax (gseg only, no bias) ----
template<int KSTEPS>
__global__ __launch_bounds__(256) void k_convmax_mfma(
    const u16* __restrict__ Wb, const u16* __restrict__ Xb,
    u32* __restrict__ gmaxEnc, int gstride, int g_off, double* __restrict__ stats,
    int C, int N, int O){
  int tid=threadIdx.x, lane=tid&63, w=tid>>6;
  int b=blockIdx.z;
  int oW = blockIdx.y*64 + w*16;
  int nB = blockIdx.x*256;
  int row16 = lane&15, grp = lane>>4;
  short8v af[KSTEPS];
  const u16* Wrow = Wb + (size_t)(oW + row16)*C + grp*8;
  #pragma unroll
  for(int ks=0;ks<KSTEPS;ks++) af[ks] = *(const short8v*)(Wrow + ks*32);
  const short8v zb = {0,0,0,0,0,0,0,0};
  f32x4 acc[16];
  #pragma unroll
  for(int t=0;t<16;t++){
    int n = nB + t*16 + row16;
    bool nv = (n < N);
    const u16* Xrow = Xb + ((size_t)b*N + (nv? n:0))*C + grp*8;
    short8v bf[KSTEPS];
    #pragma unroll
    for(int ks=0;ks<KSTEPS;ks++) bf[ks] = nv ? *(const short8v*)(Xrow + ks*32) : zb;
    f32x4 a = {0.f,0.f,0.f,0.f};
    #pragma unroll
    for(int ks=0;ks<KSTEPS;ks++)
      a = __builtin_amdgcn_mfma_f32_16x16x32_bf16(af[ks], bf[ks], a, 0, 0, 0);
    acc[t]=a;
  }
  float mxr[4], s1r[4], s2r[4];
  #pragma unroll
  for(int r=0;r<4;r++){ mxr[r]=-INFINITY; s1r[r]=0.f; s2r[r]=0.f; }
  #pragma unroll
  for(int t=0;t<16;t++){
    int n = nB + t*16 + row16;
    bool nv = (n<N);
    #pragma unroll
    for(int r=0;r<4;r++){
      float y = acc[t][r];
      if(nv){ mxr[r]=fmaxf(mxr[r],y); s1r[r]+=y; s2r[r]+=y*y; }
    }
  }
  #pragma unroll
  for(int s=1;s<16;s<<=1){
    #pragma unroll
    for(int r=0;r<4;r++){
      mxr[r]=fmaxf(mxr[r], __shfl_xor(mxr[r], s));
      s1r[r]+=__shfl_xor(s1r[r], s);
      s2r[r]+=__shfl_xor(s2r[r], s);
    }
  }
  if(row16==0){
    #pragma unroll
    for(int r=0;r<4;r++){
      int o = oW + grp*4 + r;
      atomicMax(&gmaxEnc[(size_t)b*gstride + g_off + o], encf(mxr[r]));
      atomicAdd(&stats[2*o], (double)s1r[r]);
      atomicAdd(&stats[2*o+1], (double)s2r[r]);
    }
  }
}

// ---- squared norms ----
__global__ void k_sqnorm(const float* __restrict__ X, float* __restrict__ xx, int B, int ldC, int C, int N){
  int i=blockIdx.x*TPB+threadIdx.x; if(i>=B*N) return;
  int b=i/N, n=i-b*N;
  const float* p = X + ((size_t)b*ldC)*N + n;
  float s=0.f;
  for(int c=0;c<C;c++){ float x=p[(size_t)c*N]; s+=x*x; }
  xx[i]=s;
}

// ---- FUSED kNN v3 (round-0 proven code) + XCD-aware block swizzle for
// N=2048 (r7-verified: FETCH 35.6->4.4 MB). Full 32KB stripe, single pass.
// Bijective remap only; per-block work and all results identical. ----
template<int JMAX, int CT>
__global__ __launch_bounds__(256) void k_knn_fused(
    const float* __restrict__ X, const float* __restrict__ xx,
    int ldC, int KSEL, int* __restrict__ idxOut){
  const int N = JMAX*64;
  extern __shared__ float sm[];              // [4][N]
  __shared__ u64 cand[4][128];
  int tid=threadIdx.x, lane=tid&63, w=tid>>6;
  int b, row0;
  if constexpr (JMAX==32){
    int lin=blockIdx.x, xcd=lin&7, j=lin>>3;
    b = xcd + ((j>>9)<<3);
    row0 = (j&511)*4;
  } else {
    b = blockIdx.y; row0 = blockIdx.x*4;
  }
  const float* Xb = X + (size_t)b*ldC*N;
  const float* xxb = xx + (size_t)b*N;

  // ---- compute phase: 4-row gram stripe -> LDS ----
  if constexpr (JMAX==32){
    int c0 = tid*4;
    float4 acc0[4], acc1[4];
    #pragma unroll
    for(int r=0;r<4;r++){ acc0[r]=make_float4(0,0,0,0); acc1[r]=make_float4(0,0,0,0); }
    #pragma unroll 4
    for(int c=0;c<CT;c++){
      const float* Xc = Xb + (size_t)c*N;
      float4 b0 = *(const float4*)&Xc[c0];
      float4 b1 = *(const float4*)&Xc[c0+1024];
      #pragma unroll
      for(int r=0;r<4;r++){
        float a = Xc[row0+r];
        acc0[r].x += a*b0.x; acc0[r].y += a*b0.y; acc0[r].z += a*b0.z; acc0[r].w += a*b0.w;
        acc1[r].x += a*b1.x; acc1[r].y += a*b1.y; acc1[r].z += a*b1.z; acc1[r].w += a*b1.w;
      }
    }
    float4 xm0 = *(const float4*)&xxb[c0];
    float4 xm1 = *(const float4*)&xxb[c0+1024];
    #pragma unroll
    for(int r=0;r<4;r++){
      float xr = xxb[row0+r];
      float4 d0, d1;
      d0.x=2.f*acc0[r].x-xr-xm0.x; d0.y=2.f*acc0[r].y-xr-xm0.y;
      d0.z=2.f*acc0[r].z-xr-xm0.z; d0.w=2.f*acc0[r].w-xr-xm0.w;
      d1.x=2.f*acc1[r].x-xr-xm1.x; d1.y=2.f*acc1[r].y-xr-xm1.y;
      d1.z=2.f*acc1[r].z-xr-xm1.z; d1.w=2.f*acc1[r].w-xr-xm1.w;
      *(float4*)&sm[r*N + c0]        = d0;
      *(float4*)&sm[r*N + c0 + 1024] = d1;
    }
  } else {
    int tcol = (tid < N)? tid : (tid & (N-1));
    float acc[4];
    #pragma unroll
    for(int r=0;r<4;r++) acc[r]=0.f;
    #pragma unroll 4
    for(int c=0;c<CT;c++){
      const float* Xc = Xb + (size_t)c*N;
      float bv = Xc[tcol];
      #pragma unroll
      for(int r=0;r<4;r++) acc[r] += Xc[row0+r]*bv;
    }
    float xm = xxb[tcol];
    #pragma unroll
    for(int r=0;r<4;r++) sm[r*N + tcol] = 2.f*acc[r] - xxb[row0+r] - xm;
  }
  __syncthreads();

  // ---- selection phase: wave w handles row w ----
  u64* cw = cand[w];
  int r = w;
  const float* Sr = sm + (size_t)r*N;
  u32 ev[JMAX];
  if constexpr (JMAX>=4){
    #pragma unroll
    for(int ch=0;ch<JMAX/4;ch++){
      float4 v = *(const float4*)&Sr[ch*256 + lane*4];
      ev[ch*4+0]=encf(v.x); ev[ch*4+1]=encf(v.y); ev[ch*4+2]=encf(v.z); ev[ch*4+3]=encf(v.w);
    }
  } else {
    ev[0]=encf(Sr[lane]);
  }
  int* op = idxOut + ((size_t)b*N + row0 + r)*KSEL;
  if constexpr (JMAX>=8){
    u32 vmax=ev[0];
    #pragma unroll
    for(int j=1;j<JMAX;j++) vmax = vmax>ev[j]? vmax:ev[j];
    u32 lo=0u, hi=0xFFFFFFFFu;
    while(lo<hi){
      u32 d=hi-lo; u32 mid=lo+(d>>1)+(d&1u);
      int cnum=(int)__popcll(__ballot(vmax>=mid));
      if(cnum>=KSEL) lo=mid; else hi=mid-1u;
    }
    u32 T=lo;
    u64 lml=((u64)1<<lane)-1ull;
    u32 base=0;
    #pragma unroll
    for(int j=0;j<JMAX;j++){
      bool p = ev[j]>=T;
      u64 mk=__ballot(p);
      u32 pos=base+(u32)__popcll(mk&lml);
      int m = (j>>2)*256 + lane*4 + (j&3);
      if(p && pos<128u) cw[pos] = ((u64)ev[j]<<32) | (u64)(u32)(~(u32)m);
      base += (u32)__popcll(mk);
    }
    int nc=(int)base;
    if(nc<=64){
      u64 cv = cw[lane];
      if(lane>=nc) cv=0ull;
      #pragma unroll
      for(int kk=2;kk<=64;kk<<=1){
        #pragma unroll
        for(int jj=kk>>1;jj>0;jj>>=1){
          u64 p=__shfl_xor(cv,jj);
          bool takeMax=(((lane&jj)!=0)==((lane&kk)==0));
          u64 mx=cv>p?cv:p, mn=cv>p?p:cv;
          cv=takeMax?mx:mn;
        }
      }
      if(lane>=64-KSEL) op[63-lane]=(int)(~(u32)cv);
    } else if(nc<=128){
      u64 c0v=cw[lane], c1v=cw[64+lane];
      if(64+lane>=nc) c1v=0ull;
      u64 kl=~0ull;
      for(int t=0;t<KSEL;t++){
        u64 bk=(c0v<kl)?c0v:0ull;
        if(c1v<kl&&c1v>bk) bk=c1v;
        #pragma unroll
        for(int s=1;s<64;s<<=1){u64 ok=__shfl_xor(bk,s); if(ok>bk)bk=ok;}
        if(lane==0) op[t]=(int)(~(u32)bk);
        kl=bk;
      }
    } else {
      u64 kl=~0ull;
      for(int t=0;t<KSEL;t++){
        u64 bk=0ull;
        #pragma unroll
        for(int j=0;j<JMAX;j++){
          int m = (j>>2)*256 + lane*4 + (j&3);
          u64 kj=((u64)ev[j]<<32)|(u64)(u32)(~(u32)m);
          if(kj<kl&&kj>bk) bk=kj;
        }
        #pragma unroll
        for(int s=1;s<64;s<<=1){u64 ok=__shfl_xor(bk,s); if(ok>bk)bk=ok;}
        if(lane==0) op[t]=(int)(~(u32)bk);
        kl=bk;
      }
    }
  } else {
    u64 key[JMAX];
    #pragma unroll
    for(int j=0;j<JMAX;j++){
      int m = (JMAX>=4)? ((j>>2)*256 + lane*4 + (j&3)) : lane;
      key[j]=((u64)ev[j]<<32)|(u64)(u32)(~(u32)m);
    }
    u64 kl=~0ull;
    for(int t=0;t<KSEL;t++){
      u64 bk=0ull;
      #pragma unroll
      for(int j=0;j<JMAX;j++){ u64 kj=key[j]; if(kj<kl&&kj>bk) bk=kj; }
      #pragma unroll
      for(int s=1;s<64;s<<=1){u64 ok=__shfl_xor(bk,s); if(ok>bk)bk=ok;}
      if(lane==0) op[t]=(int)(~(u32)bk);
      kl=bk;
    }
  }
}

// ---- full bitonic sort top-K for pools: thread-count-agnostic network
// (index-based compare-exchange -> identical results for any blockDim).
// Launched with 1024 threads at M=2048 (4x fewer strided iters/pass). ----
__global__ void k_topk_sort(const float* __restrict__ S, int M, int K,
                            int* __restrict__ idxOut, float* __restrict__ valOut){
  extern __shared__ u64 key[];
  int b=blockIdx.x, tid=threadIdx.x, bd=blockDim.x;
  const float* Sr = S + (size_t)b*M;
  for(int i=tid;i<M;i+=bd)
    key[i] = ((u64)(~encf(Sr[i]))<<32) | (u32)i;
  __syncthreads();
  for(int k=2;k<=M;k<<=1){
    for(int j=k>>1;j>0;j>>=1){
      for(int i=tid;i<M;i+=bd){
        int ixj=i^j;
        if(ixj>i){
          u64 a=key[i], c=key[ixj];
          bool up=((i&k)==0);
          if(up ? (a>c) : (a<c)){ key[i]=c; key[ixj]=a; }
        }
      }
      __syncthreads();
    }
  }
  for(int p=tid;p<K;p+=bd){
    u64 kk=key[p];
    idxOut[(size_t)b*K+p]=(int)(u32)(kk&0xFFFFFFFFull);
    valOut[(size_t)b*K+p]=decf(~(u32)(kk>>32));
  }
}

// ---- u = wA.x ; v = (wB-wA).x — 8-output tiled version. ----
__global__ __launch_bounds__(256) void k_uv_t(
    const float* __restrict__ X, int ldC, const float* __restrict__ W,
    float* __restrict__ U, float* __restrict__ V, int C, int N, int O){
  extern __shared__ float wsm[];             // [8][C][2]
  int tid=threadIdx.x, b=blockIdx.z;
  int o0=blockIdx.y*8;
  for(int i=tid;i<8*C;i+=TPB){
    int o=i/C, c=i-o*C;
    const float* Wr = W + (size_t)(o0+o)*2*C;
    float wa=Wr[c], wb=Wr[C+c];
    wsm[(size_t)(o*C+c)*2  ]=wa;
    wsm[(size_t)(o*C+c)*2+1]=wb-wa;
  }
  __syncthreads();
  int n=blockIdx.x*TPB+tid;
  bool act=(n<N); int nc=act? n:0;
  const float* Xb = X + ((size_t)b*ldC)*N + nc;
  float u[8], v[8];
  #pragma unroll
  for(int o=0;o<8;o++){ u[o]=0.f; v[o]=0.f; }
  for(int c=0;c<C;c++){
    float x = Xb[(size_t)c*N];
    #pragma unroll
    for(int o=0;o<8;o++){
      float2 wv = *(const float2*)&wsm[(size_t)(o*C+c)*2];
      u[o] += wv.x*x;
      v[o] += wv.y*x;
    }
  }
  if(act){
    #pragma unroll
    for(int o=0;o<8;o++){
      size_t off=((size_t)b*O+o0+o)*N+n;
      U[off]=u[o]; V[off]=v[o];
    }
  }
}

// ---- neighbor reduce ----
template<int KT, int OT>
__global__ void k_nbr_t(const float* __restrict__ U, const float* __restrict__ V, const int* __restrict__ idx,
                        float* __restrict__ outBase, int ldCout, int ch_off,
                        double* __restrict__ stats, int O, int N){
  __shared__ double redS[4][OT], redQ[4][OT];
  int tid=threadIdx.x, lane=tid&63, wv=tid>>6;
  int n = blockIdx.x*TPB+tid;
  int o0 = blockIdx.y*OT, b = blockIdx.z;
  bool act = (n<N);
  int nc = act? n : (N-1);
  int jr[KT];
  const int* jp = idx + ((size_t)b*N+nc)*KT;
  #pragma unroll
  for(int k=0;k<KT;k++){ int j=jp[k]; jr[k] = ((unsigned)j<(unsigned)N)? j : 0; }
  for(int oo=0;oo<OT;oo++){
    const float* Ur = U + ((size_t)b*O+o0+oo)*N;
    float mx=-INFINITY, s1=0.f, s2=0.f;
    #pragma unroll
    for(int k=0;k<KT;k++){ float u=Ur[jr[k]]; mx=fmaxf(mx,u); s1+=u; s2+=u*u; }
    float v = V[((size_t)b*O+o0+oo)*N+nc];
    if(act) outBase[((size_t)b*ldCout+ch_off+o0+oo)*N+n] = mx+v;
    double cs = act ? ((double)s1 + (double)KT*(double)v) : 0.0;
    double cq = act ? ((double)s2 + 2.0*(double)v*(double)s1 + (double)KT*(double)v*(double)v) : 0.0;
    #pragma unroll
    for(int s=1;s<64;s<<=1){ cs += __shfl_xor(cs,s); cq += __shfl_xor(cq,s); }
    if(lane==0){ redS[wv][oo]=cs; redQ[wv][oo]=cq; }
  }
  __syncthreads();
  if(tid<OT){
    double s=0,q=0;
    #pragma unroll
    for(int w=0;w<4;w++){ s+=redS[w][tid]; q+=redQ[w][tid]; }
    atomicAdd(&stats[2*(o0+tid)], s);
    atomicAdd(&stats[2*(o0+tid)+1], q);
  }
}

// ---- finalize BN + lrelu in place ----
__global__ void k_bnact(float* __restrict__ out, int ldCout, int ch_off, const double* __restrict__ stats,
                        int O, int N, double cnt){
  int n=blockIdx.x*TPB+threadIdx.x; if(n>=N) return;
  int o=blockIdx.y, b=blockIdx.z;
  double m=stats[2*o]/cnt;
  double var=stats[2*o+1]/cnt - m*m;
  float s=rsqrtf((float)var+EPSV);
  size_t p=((size_t)b*ldCout+ch_off+o)*N+n;
  float h=out[p];
  out[p] = lrelu((float)((double)h-m)*s);
}

// ---- f32 conv1 + max (+stats) — pools only ----
template<int PTS>
__global__ void k_convmax(const float* __restrict__ X, int ldC, const float* __restrict__ W, const float* __restrict__ bias,
                          u32* __restrict__ gmaxEnc, int gstride, int g_off, double* __restrict__ stats,
                          int C, int N, int O){
  __shared__ float red[4*16*3];
  int tid=threadIdx.x, ot=blockIdx.y, b=blockIdx.z;
  int lane=tid&63, wv=tid>>6;
  int n0 = blockIdx.x*TPB*PTS + tid*PTS;
  bool act = (n0 < N);
  int n0c = act ? n0 : (N-PTS);
  const float* Xb = X + ((size_t)b*ldC)*N;
  const float* Wr = W + (size_t)ot*16*C;
  float acc[16][PTS];
  #pragma unroll
  for(int oo=0;oo<16;oo++)
    #pragma unroll
    for(int p=0;p<PTS;p++) acc[oo][p]=0.f;
  for(int c=0;c<C;c+=4){
    float xv[4][PTS];
    #pragma unroll
    for(int cc=0;cc<4;cc++){
      if(PTS==4){
        float4 t = *(const float4*)&Xb[(size_t)(c+cc)*N + n0c];
        xv[cc][0]=t.x; xv[cc][1]=t.y; xv[cc][2]=t.z; xv[cc][3]=t.w;
      } else {
        xv[cc][0]=Xb[(size_t)(c+cc)*N + n0c];
      }
    }
    #pragma unroll
    for(int oo=0;oo<16;oo++){
      float w0=Wr[oo*C+c], w1=Wr[oo*C+c+1], w2=Wr[oo*C+c+2], w3=Wr[oo*C+c+3];
      #pragma unroll
      for(int p=0;p<PTS;p++)
        acc[oo][p] += w0*xv[0][p] + w1*xv[1][p] + w2*xv[2][p] + w3*xv[3][p];
    }
  }
  bool hs = (stats!=nullptr);
  #pragma unroll
  for(int oo=0;oo<16;oo++){
    float bval = bias? bias[ot*16+oo] : 0.f;
    float mx=-INFINITY, s1=0.f, s2=0.f;
    #pragma unroll
    for(int p=0;p<PTS;p++){
      float y=acc[oo][p]+bval;
      if(act && n0+p<N){ mx=fmaxf(mx,y); s1+=y; s2+=y*y; }
    }
    #pragma unroll
    for(int s=1;s<64;s<<=1){
      mx=fmaxf(mx,__shfl_xor(mx,s));
      if(hs){ s1+=__shfl_xor(s1,s); s2+=__shfl_xor(s2,s); }
    }
    if(lane==0){ red[(wv*16+oo)*3]=mx; red[(wv*16+oo)*3+1]=s1; red[(wv*16+oo)*3+2]=s2; }
  }
  __syncthreads();
  if(tid<16){
    int oo=tid, o=ot*16+oo;
    float mx=red[oo*3], s1=red[oo*3+1], s2=red[oo*3+2];
    #pragma unroll
    for(int w=1;w<4;w++){ mx=fmaxf(mx,red[(w*16+oo)*3]); s1+=red[(w*16+oo)*3+1]; s2+=red[(w*16+oo)*3+2]; }
    atomicMax(&gmaxEnc[(size_t)b*gstride+g_off+o], encf(mx));
    if(hs){ atomicAdd(&stats[2*o],(double)s1); atomicAdd(&stats[2*o+1],(double)s2); }
  }
}

// ---- g = lrelu(bn(max over n)) ----
__global__ void k_gfinal(const u32* __restrict__ gmaxEnc, int gstride, int g_off, const double* __restrict__ stats,
                         float* __restrict__ G, int B, int O, double cnt){
  int i=blockIdx.x*TPB+threadIdx.x; if(i>=B*O) return;
  int b=i/O, o=i-b*O;
  double m=stats[2*o]/cnt;
  double var=stats[2*o+1]/cnt - m*m;
  float s=rsqrtf((float)var+EPSV);
  float x=decf(gmaxEnc[(size_t)b*gstride+g_off+o]);
  G[(size_t)b*gstride+g_off+o]=lrelu((float)((double)x-m)*s);
}

// ---- pool attention scores ----
__global__ void k_scores(const float* __restrict__ X, int ldC, const u32* __restrict__ vecEnc,
                         float* __restrict__ sc, int C, int N){
  int n=blockIdx.x*TPB+threadIdx.x; if(n>=N) return;
  int b=blockIdx.y;
  const float* Xb = X + ((size_t)b*ldC)*N + n;
  double s=0;
  for(int c=0;c<C;c++) s += (double)Xb[(size_t)c*N]*(double)decf(vecEnc[(size_t)b*C+c]);
  float sf=(float)s;
  sc[(size_t)b*N+n]=1.f/(1.f+expf(-sf));
}

// ---- pool gather ----
__global__ void k_pgather(const float* __restrict__ xyz, int ldCx, const float* __restrict__ feat, int ldCf,
                          const int* __restrict__ pidx, const float* __restrict__ pval,
                          float* __restrict__ nodeOut, float* __restrict__ nfOut, int Cf, int Nin, int Kp){
  int b=blockIdx.y;
  int i=blockIdx.x*TPB+threadIdx.x;
  int total=(3+Cf)*Kp; if(i>=total) return;
  int c=i/Kp, p=i-c*Kp;
  int j=pidx[(size_t)b*Kp+p]; if((unsigned)j>=(unsigned)Nin) j=0;
  float v=pval[(size_t)b*Kp+p];
  if(c<3) nodeOut[((size_t)b*3+c)*Kp+p]=xyz[((size_t)b*ldCx+c)*Nin+j]*v;
  else { int cf=c-3; nfOut[((size_t)b*Cf+cf)*Kp+p]=feat[((size_t)b*ldCf+cf)*Nin+j]*v; }
}

// ---- fc: wave-per-output ----
__global__ void k_fc_wave(const float* __restrict__ A, const float* __restrict__ W, const float* __restrict__ bias,
                          float* __restrict__ Y, int B, int IN, int OUT){
  int gw = (blockIdx.x*blockDim.x + threadIdx.x) >> 6;
  if(gw >= B*OUT) return;
  int lane = threadIdx.x & 63;
  int b = gw/OUT, j = gw - b*OUT;
  const float4* a4 = (const float4*)(A + (size_t)b*IN);
  const float4* w4 = (const float4*)(W + (size_t)j*IN);
  int n4 = IN >> 2;
  float s = 0.f;
  for(int t=lane; t<n4; t+=64){
    float4 av=a4[t], wv=w4[t];
    s += av.x*wv.x + av.y*wv.y + av.z*wv.z + av.w*wv.w;
  }
  #pragma unroll
  for(int sh=1; sh<64; sh<<=1) s += __shfl_xor(s, sh);
  if(lane==0) Y[gw] = s + (bias? bias[j]:0.f);
}

// ---- BN over batch axis + lrelu ----
__global__ void k_bnb(const float* __restrict__ Y, float* __restrict__ H, int B, int F){
  int f=blockIdx.x*TPB+threadIdx.x; if(f>=F) return;
  double s=0,q=0;
  for(int b=0;b<B;b++){ double y=Y[(size_t)b*F+f]; s+=y; q+=y*y; }
  double m=s/B, var=q/B-m*m;
  float sc=rsqrtf((float)var+EPSV);
  for(int b=0;b<B;b++){ float y=Y[(size_t)b*F+f]; H[(size_t)b*F+f]=lrelu((float)((double)y-m)*sc); }
}

// ---- pack outputs ----
__global__ void k_out(const float* __restrict__ OUTF, const float* __restrict__ N1v, const float* __restrict__ N2v,
                      void* __restrict__ dout, const int* __restrict__ flag){
  int i=blockIdx.x*TPB+threadIdx.x; if(i>=16000) return;
  float v = (i<640)? OUTF[i] : (i<12928)? N1v[i-640] : N2v[i-12928];
  if(*flag) ((float*)dout)[i]=v; else ((u16*)dout)[i]=f2b(v);
}

extern "C" void kernel_launch(void* const* d_in, const int* in_sizes, int n_in,
                              void* d_out, int out_size, void* d_ws, size_t ws_size,
                              hipStream_t stream){
  const int B=16;
  char* basep=(char*)d_ws; size_t off=0;
  auto alloc=[&](size_t elems, size_t esz)->void*{
    off=(off+255)&~(size_t)255; void* p=basep+off; off+=elems*esz; return p;
  };
  const int NINP=18;
  const int insz[NINP]={98304,384,8192,131072,32768,32768,262144,131072,262144,16384,128,65536,256,1572864,131072,256,10240,40};
  float* F[NINP];
  for(int i=0;i<NINP;i++) F[i]=(float*)alloc((size_t)insz[i],4);
  float* XF=F[0];
  float *W1F=F[1],*W2F=F[2],*W2MF=F[3],*W3F=F[4],*W4F=F[5],*W4MF=F[6],*W5F=F[7],*W5MF=F[8],
        *WP1F=F[9],*BP1F=F[10],*WP2F=F[11],*BP2F=F[12],*WL1F=F[13],*WL2F=F[14],*BL2F=F[15],*WL3F=F[16],*BL3F=F[17];
  float* XX  =(float*)alloc((size_t)16*2048,4);
  float* U   =(float*)alloc((size_t)16*64*2048,4);
  float* V   =(float*)alloc((size_t)16*64*2048,4);
  float* XT1 =(float*)alloc((size_t)16*128*2048,4);
  float* XT2 =(float*)alloc((size_t)16*256*256,4);
  float* NF1 =(float*)alloc((size_t)16*128*256,4);
  float* NF2 =(float*)alloc((size_t)16*256*64,4);
  float* X5  =(float*)alloc((size_t)16*256*64,4);
  float* NODE1=(float*)alloc((size_t)16*3*256,4);
  float* NODE2=(float*)alloc((size_t)16*3*64,4);
  float* SCORES=(float*)alloc((size_t)16*2048,4);
  float* PVAL1=(float*)alloc((size_t)16*256,4);
  float* PVAL2=(float*)alloc((size_t)16*64,4);
  float* G   =(float*)alloc((size_t)16*3072,4);
  float* Y1  =(float*)alloc((size_t)16*512,4);
  float* H1  =(float*)alloc((size_t)16*512,4);
  float* Y2  =(float*)alloc((size_t)16*256,4);
  float* H2  =(float*)alloc((size_t)16*256,4);
  float* OUTF=(float*)alloc((size_t)16*40,4);
  u32* GMAX  =(u32*)alloc((size_t)16*3072,4);
  u32* VECENC=(u32*)alloc((size_t)16*256,4);
  int* IDX   =(int*)alloc((size_t)16*2048*20,4);
  int* PIDX1 =(int*)alloc((size_t)16*256,4);
  int* PIDX2 =(int*)alloc((size_t)16*64,4);
  double* STATS=(double*)alloc((size_t)2*1024,8);
  int* FLAG  =(int*)alloc(64,4);
  u16* XTB  =(u16*)alloc((size_t)16*2048*128,2);
  u16* WB2M =(u16*)alloc((size_t)131072,2);
  u16* WB4M =(u16*)alloc((size_t)262144,2);
  u16* WB5M =(u16*)alloc((size_t)262144,2);

  k_detect<<<dim3(1),dim3(TPB),0,stream>>>((const u16*)d_in[1], insz[1], FLAG);
  CvtArgs ca;
  for(int i=0;i<NINP;i++){ ca.s[i]=d_in[i]; ca.d[i]=F[i]; ca.n[i]=insz[i]; }
  k_cvt_all<<<dim3(64,NINP),dim3(TPB),0,stream>>>(ca, FLAG);
  k_castw<<<dim3((131072+TPB-1)/TPB),dim3(TPB),0,stream>>>(W2MF,WB2M,131072);
  k_castw<<<dim3((262144+TPB-1)/TPB),dim3(TPB),0,stream>>>(W4MF,WB4M,262144);
  k_castw<<<dim3((262144+TPB-1)/TPB),dim3(TPB),0,stream>>>(W5MF,WB5M,262144);

  auto knn=[&](const float* X, int ldC, int C, int N, int K){
    k_sqnorm<<<dim3((B*N+TPB-1)/TPB),dim3(TPB),0,stream>>>(X,XX,B,ldC,C,N);
    size_t shm=(size_t)4*N*4;
    if(N==2048 && C==3)       k_knn_fused<32,3>  <<<dim3(8192),dim3(256),shm,stream>>>(X,XX,ldC,K,IDX);
    else if(N==2048)          k_knn_fused<32,64> <<<dim3(8192),dim3(256),shm,stream>>>(X,XX,ldC,K,IDX);
    else if(N==256)           k_knn_fused<4,128> <<<dim3(N/4,B),dim3(256),shm,stream>>>(X,XX,ldC,K,IDX);
    else                      k_knn_fused<1,256> <<<dim3(N/4,B),dim3(256),shm,stream>>>(X,XX,ldC,K,IDX);
  };

  auto graph_conv=[&](const float* X, int ldC, int C, int N, int K, const float* W, int O,
                      float* outBase, int ldCout, int ch_off){
    knn(X,ldC,C,N,K);
    size_t wshm=(size_t)8*C*2*4;
    k_uv_t<<<dim3((N+TPB-1)/TPB,O/8,B),dim3(TPB),wshm,stream>>>(X,ldC,W,U,V,C,N,O);
    hipMemsetAsync(STATS,0,2*(size_t)O*sizeof(double),stream);
    dim3 g((N+TPB-1)/TPB, O/8, B);
    if(K==20)      k_nbr_t<20,8><<<g,dim3(TPB),0,stream>>>(U,V,IDX,outBase,ldCout,ch_off,STATS,O,N);
    else if(K==10) k_nbr_t<10,8><<<g,dim3(TPB),0,stream>>>(U,V,IDX,outBase,ldCout,ch_off,STATS,O,N);
    else           k_nbr_t<5,8> <<<g,dim3(TPB),0,stream>>>(U,V,IDX,outBase,ldCout,ch_off,STATS,O,N);
    double cnt=(double)B*(double)N*(double)K;
    k_bnact<<<dim3((N+TPB-1)/TPB,O,B),dim3(TPB),0,stream>>>(outBase,ldCout,ch_off,STATS,O,N,cnt);
  };

  auto convmax_f32=[&](const float* X,int ldC,const float* W,const float* bias,
                   u32* gmax,int gstride,int g_off,double* stats,int C,int N,int O){
    if(N>=1024) k_convmax<4><<<dim3((N+TPB*4-1)/(TPB*4),O/16,B),dim3(TPB),0,stream>>>(X,ldC,W,bias,gmax,gstride,g_off,stats,C,N,O);
    else        k_convmax<1><<<dim3((N+TPB-1)/TPB,O/16,B),dim3(TPB),0,stream>>>(X,ldC,W,bias,gmax,gstride,g_off,stats,C,N,O);
  };

  auto pool=[&](const float* xyzF,int ldCx,const float* featF,int ldCf,int Cf,int Nin,
                const float* WP,const float* BP,int Op,int Kp,
                float* nodeOut,float* nfOut,int* pidx,float* pval){
    hipMemsetAsync(VECENC,0,(size_t)B*Op*4,stream);
    convmax_f32(featF,ldCf,WP,BP,VECENC,Op,0,(double*)nullptr,Cf,Nin,Op);
    k_scores<<<dim3((Nin+TPB-1)/TPB,B),dim3(TPB),0,stream>>>(featF,ldCf,VECENC,SCORES,Cf,Nin);
    int tsort = (Nin>=1024)? 1024 : TPB;
    k_topk_sort<<<dim3(B),dim3(tsort),(size_t)Nin*8,stream>>>(SCORES,Nin,Kp,pidx,pval);
    k_pgather<<<dim3(((3+Cf)*Kp+TPB-1)/TPB,B),dim3(TPB),0,stream>>>(xyzF,ldCx,featF,ldCf,pidx,pval,nodeOut,nfOut,Cf,Nin,Kp);
  };

  auto gseg=[&](const float* X,int ldC,int C,int N,const u16* WBc,int g_off,double cnt){
    hipMemsetAsync(STATS,0,2*1024*sizeof(double),stream);
    k_xpose_bf<<<dim3((N+31)/32,(C+31)/32,B),dim3(256),0,stream>>>(X,XTB,ldC,C,N);
    dim3 g((N+255)/256, 1024/64, B);
    if(C==128) k_convmax_mfma<4><<<g,dim3(256),0,stream>>>(WBc,XTB,GMAX,3072,g_off,STATS,C,N,1024);
    else       k_convmax_mfma<8><<<g,dim3(256),0,stream>>>(WBc,XTB,GMAX,3072,g_off,STATS,C,N,1024);
    k_gfinal<<<dim3((B*1024+TPB-1)/TPB),dim3(TPB),0,stream>>>(GMAX,3072,g_off,STATS,G,B,1024,cnt);
  };

  graph_conv(XF,3,3,2048,20,W1F,64,XT1,128,0);
  graph_conv(XT1,128,64,2048,20,W2F,64,XT1,128,64);
  hipMemsetAsync(GMAX,0,(size_t)16*3072*4,stream);
  gseg(XT1,128,128,2048,WB2M,0,(double)16*2048);
  pool(XF,3,XT1,128,128,2048,WP1F,BP1F,128,256,NODE1,NF1,PIDX1,PVAL1);
  graph_conv(NF1,128,128,256,10,W3F,128,XT2,256,0);
  graph_conv(XT2,256,128,256,10,W4F,128,XT2,256,128);
  gseg(XT2,256,256,256,WB4M,1024,(double)16*256);
  pool(NODE1,3,XT2,256,256,256,WP2F,BP2F,256,64,NODE2,NF2,PIDX2,PVAL2);
  graph_conv(NF2,256,256,64,5,W5F,256,X5,256,0);
  gseg(X5,256,256,64,WB5M,2048,(double)16*64);
  k_fc_wave<<<dim3((16*512*64+TPB-1)/TPB),dim3(TPB),0,stream>>>(G,WL1F,(const float*)nullptr,Y1,16,3072,512);
  k_bnb<<<dim3((512+TPB-1)/TPB),dim3(TPB),0,stream>>>(Y1,H1,16,512);
  k_fc_wave<<<dim3((16*256*64+TPB-1)/TPB),dim3(TPB),0,stream>>>(H1,WL2F,BL2F,Y2,16,512,256);
  k_bnb<<<dim3((256+TPB-1)/TPB),dim3(TPB),0,stream>>>(Y2,H2,16,256);
  k_fc_wave<<<dim3((16*40*64+TPB-1)/TPB),dim3(TPB),0,stream>>>(H2,WL3F,BL3F,OUTF,16,256,40);
  k_out<<<dim3((16000+TPB-1)/TPB),dim3(TPB),0,stream>>>(OUTF,NODE1,NODE2,(u16*)d_out,FLAG);
}

// Round 10
// 1086.641 us; speedup vs baseline: 1.0533x; 1.0001x over previous
//
#include <hip/hip_runtime.h>
#include <cmath>
#include <cstdint>
#include <cstddef>

typedef unsigned int u32;
typedef unsigned short u16;
typedef unsigned long long u64;
typedef __attribute__((ext_vector_type(8))) short short8v;
typedef __attribute__((ext_vector_type(4))) float f32x4;

#define TPB 256
#define EPSV 1e-5f
#define SLP 0.2f

__device__ __forceinline__ float lrelu(float x){ return x >= 0.f ? x : SLP*x; }
__device__ __forceinline__ u32 encf(float f){ u32 u=__float_as_uint(f); return (u&0x80000000u)? ~u : (u|0x80000000u); }
__device__ __forceinline__ float decf(u32 e){ return (e&0x80000000u)? __uint_as_float(e&0x7FFFFFFFu) : __uint_as_float(~e); }
__device__ __forceinline__ u16 f2b(float f){ u32 u=__float_as_uint(f); return (u16)((u + 0x7FFFu + ((u>>16)&1u))>>16); }
__device__ __forceinline__ float b2f(u16 h){ return __uint_as_float(((u32)h)<<16); }

// ---- dtype detector ----
__global__ void k_detect(const u16* __restrict__ raw, int n, int* __restrict__ flag){
  __shared__ float red[TPB];
  int tid=threadIdx.x; float m=0.f;
  for(int i=tid;i<n;i+=TPB){
    float v=fabsf(b2f(raw[i]));
    if(!isnan(v) && !isinf(v) && v>m) m=v;
  }
  red[tid]=m; __syncthreads();
  for(int s=TPB/2;s>0;s>>=1){ if(tid<s) red[tid]=fmaxf(red[tid],red[tid+s]); __syncthreads(); }
  if(tid==0) *flag = (red[0] > 1000.f) ? 1 : 0;
}

// ---- all-inputs -> f32 ----
struct CvtArgs{ const void* s[18]; float* d[18]; int n[18]; };
__global__ void k_cvt_all(CvtArgs a, const int* __restrict__ flag){
  int z=blockIdx.y; int n=a.n[z]; int f=*flag;
  const void* s=a.s[z]; float* d=a.d[z];
  for(int i=blockIdx.x*TPB+threadIdx.x; i<n; i+=gridDim.x*TPB)
    d[i] = f ? ((const float*)s)[i] : b2f(((const u16*)s)[i]);
}

// ---- f32 -> bf16 cast (weights) ----
__global__ void k_castw(const float* __restrict__ W, u16* __restrict__ Wb, int n){
  int i=blockIdx.x*TPB+threadIdx.x; if(i<n) Wb[i]=f2b(W[i]);
}

// ---- transpose+cast: X [b][c][N](ldC rows used C) -> bf16 [b][n][C] ----
__global__ void k_xpose_bf(const float* __restrict__ X, u16* __restrict__ Xb,
                           int ldC, int C, int N){
  __shared__ float t[32][33];
  int b=blockIdx.z;
  int c0=blockIdx.y*32, n0=blockIdx.x*32;
  int tx=threadIdx.x&31, ty=threadIdx.x>>5;
  const float* Xs = X + (size_t)b*ldC*N;
  #pragma unroll
  for(int i=0;i<4;i++){
    int c=c0+ty+i*8;
    t[ty+i*8][tx] = (c<C && n0+tx<N) ? Xs[(size_t)c*N + n0+tx] : 0.f;
  }
  __syncthreads();
  u16* Ob = Xb + (size_t)b*N*C;
  #pragma unroll
  for(int i=0;i<4;i++){
    int n=n0+ty+i*8;
    if(n<N && c0+tx<C) Ob[(size_t)n*C + c0+tx] = f2b(t[tx][ty+i*8]);
  }
}

// ---- MFMA convmax (gseg only, no bias) ----
template<int KSTEPS>
__global__ __launch_bounds__(256) void k_convmax_mfma(
    const u16* __restrict__ Wb, const u16* __restrict__ Xb,
    u32* __restrict__ gmaxEnc, int gstride, int g_off, double* __restrict__ stats,
    int C, int N, int O){
  int tid=threadIdx.x, lane=tid&63, w=tid>>6;
  int b=blockIdx.z;
  int oW = blockIdx.y*64 + w*16;
  int nB = blockIdx.x*256;
  int row16 = lane&15, grp = lane>>4;
  short8v af[KSTEPS];
  const u16* Wrow = Wb + (size_t)(oW + row16)*C + grp*8;
  #pragma unroll
  for(int ks=0;ks<KSTEPS;ks++) af[ks] = *(const short8v*)(Wrow + ks*32);
  const short8v zb = {0,0,0,0,0,0,0,0};
  f32x4 acc[16];
  #pragma unroll
  for(int t=0;t<16;t++){
    int n = nB + t*16 + row16;
    bool nv = (n < N);
    const u16* Xrow = Xb + ((size_t)b*N + (nv? n:0))*C + grp*8;
    short8v bf[KSTEPS];
    #pragma unroll
    for(int ks=0;ks<KSTEPS;ks++) bf[ks] = nv ? *(const short8v*)(Xrow + ks*32) : zb;
    f32x4 a = {0.f,0.f,0.f,0.f};
    #pragma unroll
    for(int ks=0;ks<KSTEPS;ks++)
      a = __builtin_amdgcn_mfma_f32_16x16x32_bf16(af[ks], bf[ks], a, 0, 0, 0);
    acc[t]=a;
  }
  float mxr[4], s1r[4], s2r[4];
  #pragma unroll
  for(int r=0;r<4;r++){ mxr[r]=-INFINITY; s1r[r]=0.f; s2r[r]=0.f; }
  #pragma unroll
  for(int t=0;t<16;t++){
    int n = nB + t*16 + row16;
    bool nv = (n<N);
    #pragma unroll
    for(int r=0;r<4;r++){
      float y = acc[t][r];
      if(nv){ mxr[r]=fmaxf(mxr[r],y); s1r[r]+=y; s2r[r]+=y*y; }
    }
  }
  #pragma unroll
  for(int s=1;s<16;s<<=1){
    #pragma unroll
    for(int r=0;r<4;r++){
      mxr[r]=fmaxf(mxr[r], __shfl_xor(mxr[r], s));
      s1r[r]+=__shfl_xor(s1r[r], s);
      s2r[r]+=__shfl_xor(s2r[r], s);
    }
  }
  if(row16==0){
    #pragma unroll
    for(int r=0;r<4;r++){
      int o = oW + grp*4 + r;
      atomicMax(&gmaxEnc[(size_t)b*gstride + g_off + o], encf(mxr[r]));
      atomicAdd(&stats[2*o], (double)s1r[r]);
      atomicAdd(&stats[2*o+1], (double)s2r[r]);
    }
  }
}

// ---- squared norms ----
__global__ void k_sqnorm(const float* __restrict__ X, float* __restrict__ xx, int B, int ldC, int C, int N){
  int i=blockIdx.x*TPB+threadIdx.x; if(i>=B*N) return;
  int b=i/N, n=i-b*N;
  const float* p = X + ((size_t)b*ldC)*N + n;
  float s=0.f;
  for(int c=0;c<C;c++){ float x=p[(size_t)c*N]; s+=x*x; }
  xx[i]=s;
}

// ---- FUSED kNN (r7 structure: 32KB stripe + XCD swizzle) with two
// provably-identical selection replacements:
// (a) threshold T = KSEL-th largest lane-max via 64-lane bitonic (equals
//     the binary search's max-feasible T exactly);
// (b) ballot-free compaction: per-lane count -> shuffle prefix-sum ->
//     per-lane writes. Candidate SET and nc identical; order irrelevant
//     (nc<=64 fully sorts; nc<=128 repeated-max; nc>128 ignores cand). ----
template<int JMAX, int CT>
__global__ __launch_bounds__(256) void k_knn_fused(
    const float* __restrict__ X, const float* __restrict__ xx,
    int ldC, int KSEL, int* __restrict__ idxOut){
  const int N = JMAX*64;
  extern __shared__ float sm[];              // [4][N]
  __shared__ u64 cand[4][128];
  int tid=threadIdx.x, lane=tid&63, w=tid>>6;
  int b, row0;
  if constexpr (JMAX==32){
    int lin=blockIdx.x, xcd=lin&7, j=lin>>3;
    b = xcd + ((j>>9)<<3);
    row0 = (j&511)*4;
  } else {
    b = blockIdx.y; row0 = blockIdx.x*4;
  }
  const float* Xb = X + (size_t)b*ldC*N;
  const float* xxb = xx + (size_t)b*N;

  // ---- compute phase: 4-row gram stripe -> LDS ----
  if constexpr (JMAX==32){
    int c0 = tid*4;
    float4 acc0[4], acc1[4];
    #pragma unroll
    for(int r=0;r<4;r++){ acc0[r]=make_float4(0,0,0,0); acc1[r]=make_float4(0,0,0,0); }
    #pragma unroll 4
    for(int c=0;c<CT;c++){
      const float* Xc = Xb + (size_t)c*N;
      float4 b0 = *(const float4*)&Xc[c0];
      float4 b1 = *(const float4*)&Xc[c0+1024];
      #pragma unroll
      for(int r=0;r<4;r++){
        float a = Xc[row0+r];
        acc0[r].x += a*b0.x; acc0[r].y += a*b0.y; acc0[r].z += a*b0.z; acc0[r].w += a*b0.w;
        acc1[r].x += a*b1.x; acc1[r].y += a*b1.y; acc1[r].z += a*b1.z; acc1[r].w += a*b1.w;
      }
    }
    float4 xm0 = *(const float4*)&xxb[c0];
    float4 xm1 = *(const float4*)&xxb[c0+1024];
    #pragma unroll
    for(int r=0;r<4;r++){
      float xr = xxb[row0+r];
      float4 d0, d1;
      d0.x=2.f*acc0[r].x-xr-xm0.x; d0.y=2.f*acc0[r].y-xr-xm0.y;
      d0.z=2.f*acc0[r].z-xr-xm0.z; d0.w=2.f*acc0[r].w-xr-xm0.w;
      d1.x=2.f*acc1[r].x-xr-xm1.x; d1.y=2.f*acc1[r].y-xr-xm1.y;
      d1.z=2.f*acc1[r].z-xr-xm1.z; d1.w=2.f*acc1[r].w-xr-xm1.w;
      *(float4*)&sm[r*N + c0]        = d0;
      *(float4*)&sm[r*N + c0 + 1024] = d1;
    }
  } else {
    int tcol = (tid < N)? tid : (tid & (N-1));
    float acc[4];
    #pragma unroll
    for(int r=0;r<4;r++) acc[r]=0.f;
    #pragma unroll 4
    for(int c=0;c<CT;c++){
      const float* Xc = Xb + (size_t)c*N;
      float bv = Xc[tcol];
      #pragma unroll
      for(int r=0;r<4;r++) acc[r] += Xc[row0+r]*bv;
    }
    float xm = xxb[tcol];
    #pragma unroll
    for(int r=0;r<4;r++) sm[r*N + tcol] = 2.f*acc[r] - xxb[row0+r] - xm;
  }
  __syncthreads();

  // ---- selection phase: wave w handles row w ----
  u64* cw = cand[w];
  int r = w;
  const float* Sr = sm + (size_t)r*N;
  u32 ev[JMAX];
  if constexpr (JMAX>=4){
    #pragma unroll
    for(int ch=0;ch<JMAX/4;ch++){
      float4 v = *(const float4*)&Sr[ch*256 + lane*4];
      ev[ch*4+0]=encf(v.x); ev[ch*4+1]=encf(v.y); ev[ch*4+2]=encf(v.z); ev[ch*4+3]=encf(v.w);
    }
  } else {
    ev[0]=encf(Sr[lane]);
  }
  int* op = idxOut + ((size_t)b*N + row0 + r)*KSEL;
  if constexpr (JMAX>=8){
    u32 vmax=ev[0];
    #pragma unroll
    for(int j=1;j<JMAX;j++) vmax = vmax>ev[j]? vmax:ev[j];
    // (a) T = KSEL-th largest lane-max via bitonic sort of the 64 lane maxima.
    // Identical to binary search's "largest T with count(vmax>=T)>=KSEL".
    u32 vs = vmax;
    #pragma unroll
    for(int kk=2;kk<=64;kk<<=1){
      #pragma unroll
      for(int jj=kk>>1;jj>0;jj>>=1){
        u32 o = __shfl_xor(vs, jj);
        bool takeMax=(((lane&jj)!=0)==((lane&kk)==0));
        u32 mx = vs>o?vs:o, mn = vs>o?o:vs;
        vs = takeMax?mx:mn;
      }
    }
    u32 T = (u32)__shfl((int)vs, 64-KSEL);   // ascending sort: lane 63 = max
    // (b) ballot-free compaction
    u32 cnt=0;
    #pragma unroll
    for(int j=0;j<JMAX;j++) cnt += (ev[j]>=T) ? 1u : 0u;
    u32 pre = cnt;
    #pragma unroll
    for(int s=1;s<64;s<<=1){
      u32 t2 = __shfl_up(pre, s);
      pre += (lane>=s) ? t2 : 0u;
    }
    u32 total = (u32)__shfl((int)pre, 63);
    u32 pos = pre - cnt;
    #pragma unroll
    for(int j=0;j<JMAX;j++){
      bool p = ev[j]>=T;
      int m = (j>>2)*256 + lane*4 + (j&3);
      if(p){
        if(pos<128u) cw[pos] = ((u64)ev[j]<<32) | (u64)(u32)(~(u32)m);
        pos++;
      }
    }
    int nc=(int)total;
    if(nc<=64){
      u64 cv = cw[lane];
      if(lane>=nc) cv=0ull;
      #pragma unroll
      for(int kk=2;kk<=64;kk<<=1){
        #pragma unroll
        for(int jj=kk>>1;jj>0;jj>>=1){
          u64 p=__shfl_xor(cv,jj);
          bool takeMax=(((lane&jj)!=0)==((lane&kk)==0));
          u64 mx=cv>p?cv:p, mn=cv>p?p:cv;
          cv=takeMax?mx:mn;
        }
      }
      if(lane>=64-KSEL) op[63-lane]=(int)(~(u32)cv);
    } else if(nc<=128){
      u64 c0v=cw[lane], c1v=cw[64+lane];
      if(64+lane>=nc) c1v=0ull;
      u64 kl=~0ull;
      for(int t=0;t<KSEL;t++){
        u64 bk=(c0v<kl)?c0v:0ull;
        if(c1v<kl&&c1v>bk) bk=c1v;
        #pragma unroll
        for(int s=1;s<64;s<<=1){u64 ok=__shfl_xor(bk,s); if(ok>bk)bk=ok;}
        if(lane==0) op[t]=(int)(~(u32)bk);
        kl=bk;
      }
    } else {
      u64 kl=~0ull;
      for(int t=0;t<KSEL;t++){
        u64 bk=0ull;
        #pragma unroll
        for(int j=0;j<JMAX;j++){
          int m = (j>>2)*256 + lane*4 + (j&3);
          u64 kj=((u64)ev[j]<<32)|(u64)(u32)(~(u32)m);
          if(kj<kl&&kj>bk) bk=kj;
        }
        #pragma unroll
        for(int s=1;s<64;s<<=1){u64 ok=__shfl_xor(bk,s); if(ok>bk)bk=ok;}
        if(lane==0) op[t]=(int)(~(u32)bk);
        kl=bk;
      }
    }
  } else {
    u64 key[JMAX];
    #pragma unroll
    for(int j=0;j<JMAX;j++){
      int m = (JMAX>=4)? ((j>>2)*256 + lane*4 + (j&3)) : lane;
      key[j]=((u64)ev[j]<<32)|(u64)(u32)(~(u32)m);
    }
    u64 kl=~0ull;
    for(int t=0;t<KSEL;t++){
      u64 bk=0ull;
      #pragma unroll
      for(int j=0;j<JMAX;j++){ u64 kj=key[j]; if(kj<kl&&kj>bk) bk=kj; }
      #pragma unroll
      for(int s=1;s<64;s<<=1){u64 ok=__shfl_xor(bk,s); if(ok>bk)bk=ok;}
      if(lane==0) op[t]=(int)(~(u32)bk);
      kl=bk;
    }
  }
}

// ---- full bitonic sort top-K for pools: thread-count-agnostic network ----
__global__ void k_topk_sort(const float* __restrict__ S, int M, int K,
                            int* __restrict__ idxOut, float* __restrict__ valOut){
  extern __shared__ u64 key[];
  int b=blockIdx.x, tid=threadIdx.x, bd=blockDim.x;
  const float* Sr = S + (size_t)b*M;
  for(int i=tid;i<M;i+=bd)
    key[i] = ((u64)(~encf(Sr[i]))<<32) | (u32)i;
  __syncthreads();
  for(int k=2;k<=M;k<<=1){
    for(int j=k>>1;j>0;j>>=1){
      for(int i=tid;i<M;i+=bd){
        int ixj=i^j;
        if(ixj>i){
          u64 a=key[i], c=key[ixj];
          bool up=((i&k)==0);
          if(up ? (a>c) : (a<c)){ key[i]=c; key[ixj]=a; }
        }
      }
      __syncthreads();
    }
  }
  for(int p=tid;p<K;p+=bd){
    u64 kk=key[p];
    idxOut[(size_t)b*K+p]=(int)(u32)(kk&0xFFFFFFFFull);
    valOut[(size_t)b*K+p]=decf(~(u32)(kk>>32));
  }
}

// ---- u = wA.x ; v = (wB-wA).x — 8-output tiled version. ----
__global__ __launch_bounds__(256) void k_uv_t(
    const float* __restrict__ X, int ldC, const float* __restrict__ W,
    float* __restrict__ U, float* __restrict__ V, int C, int N, int O){
  extern __shared__ float wsm[];             // [8][C][2]
  int tid=threadIdx.x, b=blockIdx.z;
  int o0=blockIdx.y*8;
  for(int i=tid;i<8*C;i+=TPB){
    int o=i/C, c=i-o*C;
    const float* Wr = W + (size_t)(o0+o)*2*C;
    float wa=Wr[c], wb=Wr[C+c];
    wsm[(size_t)(o*C+c)*2  ]=wa;
    wsm[(size_t)(o*C+c)*2+1]=wb-wa;
  }
  __syncthreads();
  int n=blockIdx.x*TPB+tid;
  bool act=(n<N); int nc=act? n:0;
  const float* Xb = X + ((size_t)b*ldC)*N + nc;
  float u[8], v[8];
  #pragma unroll
  for(int o=0;o<8;o++){ u[o]=0.f; v[o]=0.f; }
  for(int c=0;c<C;c++){
    float x = Xb[(size_t)c*N];
    #pragma unroll
    for(int o=0;o<8;o++){
      float2 wv = *(const float2*)&wsm[(size_t)(o*C+c)*2];
      u[o] += wv.x*x;
      v[o] += wv.y*x;
    }
  }
  if(act){
    #pragma unroll
    for(int o=0;o<8;o++){
      size_t off=((size_t)b*O+o0+o)*N+n;
      U[off]=u[o]; V[off]=v[o];
    }
  }
}

// ---- neighbor reduce ----
template<int KT, int OT>
__global__ void k_nbr_t(const float* __restrict__ U, const float* __restrict__ V, const int* __restrict__ idx,
                        float* __restrict__ outBase, int ldCout, int ch_off,
                        double* __restrict__ stats, int O, int N){
  __shared__ double redS[4][OT], redQ[4][OT];
  int tid=threadIdx.x, lane=tid&63, wv=tid>>6;
  int n = blockIdx.x*TPB+tid;
  int o0 = blockIdx.y*OT, b = blockIdx.z;
  bool act = (n<N);
  int nc = act? n : (N-1);
  int jr[KT];
  const int* jp = idx + ((size_t)b*N+nc)*KT;
  #pragma unroll
  for(int k=0;k<KT;k++){ int j=jp[k]; jr[k] = ((unsigned)j<(unsigned)N)? j : 0; }
  for(int oo=0;oo<OT;oo++){
    const float* Ur = U + ((size_t)b*O+o0+oo)*N;
    float mx=-INFINITY, s1=0.f, s2=0.f;
    #pragma unroll
    for(int k=0;k<KT;k++){ float u=Ur[jr[k]]; mx=fmaxf(mx,u); s1+=u; s2+=u*u; }
    float v = V[((size_t)b*O+o0+oo)*N+nc];
    if(act) outBase[((size_t)b*ldCout+ch_off+o0+oo)*N+n] = mx+v;
    double cs = act ? ((double)s1 + (double)KT*(double)v) : 0.0;
    double cq = act ? ((double)s2 + 2.0*(double)v*(double)s1 + (double)KT*(double)v*(double)v) : 0.0;
    #pragma unroll
    for(int s=1;s<64;s<<=1){ cs += __shfl_xor(cs,s); cq += __shfl_xor(cq,s); }
    if(lane==0){ redS[wv][oo]=cs; redQ[wv][oo]=cq; }
  }
  __syncthreads();
  if(tid<OT){
    double s=0,q=0;
    #pragma unroll
    for(int w=0;w<4;w++){ s+=redS[w][tid]; q+=redQ[w][tid]; }
    atomicAdd(&stats[2*(o0+tid)], s);
    atomicAdd(&stats[2*(o0+tid)+1], q);
  }
}

// ---- finalize BN + lrelu in place ----
__global__ void k_bnact(float* __restrict__ out, int ldCout, int ch_off, const double* __restrict__ stats,
                        int O, int N, double cnt){
  int n=blockIdx.x*TPB+threadIdx.x; if(n>=N) return;
  int o=blockIdx.y, b=blockIdx.z;
  double m=stats[2*o]/cnt;
  double var=stats[2*o+1]/cnt - m*m;
  float s=rsqrtf((float)var+EPSV);
  size_t p=((size_t)b*ldCout+ch_off+o)*N+n;
  float h=out[p];
  out[p] = lrelu((float)((double)h-m)*s);
}

// ---- f32 conv1 + max (+stats) — pools only ----
template<int PTS>
__global__ void k_convmax(const float* __restrict__ X, int ldC, const float* __restrict__ W, const float* __restrict__ bias,
                          u32* __restrict__ gmaxEnc, int gstride, int g_off, double* __restrict__ stats,
                          int C, int N, int O){
  __shared__ float red[4*16*3];
  int tid=threadIdx.x, ot=blockIdx.y, b=blockIdx.z;
  int lane=tid&63, wv=tid>>6;
  int n0 = blockIdx.x*TPB*PTS + tid*PTS;
  bool act = (n0 < N);
  int n0c = act ? n0 : (N-PTS);
  const float* Xb = X + ((size_t)b*ldC)*N;
  const float* Wr = W + (size_t)ot*16*C;
  float acc[16][PTS];
  #pragma unroll
  for(int oo=0;oo<16;oo++)
    #pragma unroll
    for(int p=0;p<PTS;p++) acc[oo][p]=0.f;
  for(int c=0;c<C;c+=4){
    float xv[4][PTS];
    #pragma unroll
    for(int cc=0;cc<4;cc++){
      if(PTS==4){
        float4 t = *(const float4*)&Xb[(size_t)(c+cc)*N + n0c];
        xv[cc][0]=t.x; xv[cc][1]=t.y; xv[cc][2]=t.z; xv[cc][3]=t.w;
      } else {
        xv[cc][0]=Xb[(size_t)(c+cc)*N + n0c];
      }
    }
    #pragma unroll
    for(int oo=0;oo<16;oo++){
      float w0=Wr[oo*C+c], w1=Wr[oo*C+c+1], w2=Wr[oo*C+c+2], w3=Wr[oo*C+c+3];
      #pragma unroll
      for(int p=0;p<PTS;p++)
        acc[oo][p] += w0*xv[0][p] + w1*xv[1][p] + w2*xv[2][p] + w3*xv[3][p];
    }
  }
  bool hs = (stats!=nullptr);
  #pragma unroll
  for(int oo=0;oo<16;oo++){
    float bval = bias? bias[ot*16+oo] : 0.f;
    float mx=-INFINITY, s1=0.f, s2=0.f;
    #pragma unroll
    for(int p=0;p<PTS;p++){
      float y=acc[oo][p]+bval;
      if(act && n0+p<N){ mx=fmaxf(mx,y); s1+=y; s2+=y*y; }
    }
    #pragma unroll
    for(int s=1;s<64;s<<=1){
      mx=fmaxf(mx,__shfl_xor(mx,s));
      if(hs){ s1+=__shfl_xor(s1,s); s2+=__shfl_xor(s2,s); }
    }
    if(lane==0){ red[(wv*16+oo)*3]=mx; red[(wv*16+oo)*3+1]=s1; red[(wv*16+oo)*3+2]=s2; }
  }
  __syncthreads();
  if(tid<16){
    int oo=tid, o=ot*16+oo;
    float mx=red[oo*3], s1=red[oo*3+1], s2=red[oo*3+2];
    #pragma unroll
    for(int w=1;w<4;w++){ mx=fmaxf(mx,red[(w*16+oo)*3]); s1+=red[(w*16+oo)*3+1]; s2+=red[(w*16+oo)*3+2]; }
    atomicMax(&gmaxEnc[(size_t)b*gstride+g_off+o], encf(mx));
    if(hs){ atomicAdd(&stats[2*o],(double)s1); atomicAdd(&stats[2*o+1],(double)s2); }
  }
}

// ---- g = lrelu(bn(max over n)) ----
__global__ void k_gfinal(const u32* __restrict__ gmaxEnc, int gstride, int g_off, const double* __restrict__ stats,
                         float* __restrict__ G, int B, int O, double cnt){
  int i=blockIdx.x*TPB+threadIdx.x; if(i>=B*O) return;
  int b=i/O, o=i-b*O;
  double m=stats[2*o]/cnt;
  double var=stats[2*o+1]/cnt - m*m;
  float s=rsqrtf((float)var+EPSV);
  float x=decf(gmaxEnc[(size_t)b*gstride+g_off+o]);
  G[(size_t)b*gstride+g_off+o]=lrelu((float)((double)x-m)*s);
}

// ---- pool attention scores ----
__global__ void k_scores(const float* __restrict__ X, int ldC, const u32* __restrict__ vecEnc,
                         float* __restrict__ sc, int C, int N){
  int n=blockIdx.x*TPB+threadIdx.x; if(n>=N) return;
  int b=blockIdx.y;
  const float* Xb = X + ((size_t)b*ldC)*N + n;
  double s=0;
  for(int c=0;c<C;c++) s += (double)Xb[(size_t)c*N]*(double)decf(vecEnc[(size_t)b*C+c]);
  float sf=(float)s;
  sc[(size_t)b*N+n]=1.f/(1.f+expf(-sf));
}

// ---- pool gather ----
__global__ void k_pgather(const float* __restrict__ xyz, int ldCx, const float* __restrict__ feat, int ldCf,
                          const int* __restrict__ pidx, const float* __restrict__ pval,
                          float* __restrict__ nodeOut, float* __restrict__ nfOut, int Cf, int Nin, int Kp){
  int b=blockIdx.y;
  int i=blockIdx.x*TPB+threadIdx.x;
  int total=(3+Cf)*Kp; if(i>=total) return;
  int c=i/Kp, p=i-c*Kp;
  int j=pidx[(size_t)b*Kp+p]; if((unsigned)j>=(unsigned)Nin) j=0;
  float v=pval[(size_t)b*Kp+p];
  if(c<3) nodeOut[((size_t)b*3+c)*Kp+p]=xyz[((size_t)b*ldCx+c)*Nin+j]*v;
  else { int cf=c-3; nfOut[((size_t)b*Cf+cf)*Kp+p]=feat[((size_t)b*ldCf+cf)*Nin+j]*v; }
}

// ---- fc: wave-per-output ----
__global__ void k_fc_wave(const float* __restrict__ A, const float* __restrict__ W, const float* __restrict__ bias,
                          float* __restrict__ Y, int B, int IN, int OUT){
  int gw = (blockIdx.x*blockDim.x + threadIdx.x) >> 6;
  if(gw >= B*OUT) return;
  int lane = threadIdx.x & 63;
  int b = gw/OUT, j = gw - b*OUT;
  const float4* a4 = (const float4*)(A + (size_t)b*IN);
  const float4* w4 = (const float4*)(W + (size_t)j*IN);
  int n4 = IN >> 2;
  float s = 0.f;
  for(int t=lane; t<n4; t+=64){
    float4 av=a4[t], wv=w4[t];
    s += av.x*wv.x + av.y*wv.y + av.z*wv.z + av.w*wv.w;
  }
  #pragma unroll
  for(int sh=1; sh<64; sh<<=1) s += __shfl_xor(s, sh);
  if(lane==0) Y[gw] = s + (bias? bias[j]:0.f);
}

// ---- BN over batch axis + lrelu ----
__global__ void k_bnb(const float* __restrict__ Y, float* __restrict__ H, int B, int F){
  int f=blockIdx.x*TPB+threadIdx.x; if(f>=F) return;
  double s=0,q=0;
  for(int b=0;b<B;b++){ double y=Y[(size_t)b*F+f]; s+=y; q+=y*y; }
  double m=s/B, var=q/B-m*m;
  float sc=rsqrtf((float)var+EPSV);
  for(int b=0;b<B;b++){ float y=Y[(size_t)b*F+f]; H[(size_t)b*F+f]=lrelu((float)((double)y-m)*sc); }
}

// ---- pack outputs ----
__global__ void k_out(const float* __restrict__ OUTF, const float* __restrict__ N1v, const float* __restrict__ N2v,
                      void* __restrict__ dout, const int* __restrict__ flag){
  int i=blockIdx.x*TPB+threadIdx.x; if(i>=16000) return;
  float v = (i<640)? OUTF[i] : (i<12928)? N1v[i-640] : N2v[i-12928];
  if(*flag) ((float*)dout)[i]=v; else ((u16*)dout)[i]=f2b(v);
}

extern "C" void kernel_launch(void* const* d_in, const int* in_sizes, int n_in,
                              void* d_out, int out_size, void* d_ws, size_t ws_size,
                              hipStream_t stream){
  const int B=16;
  char* basep=(char*)d_ws; size_t off=0;
  auto alloc=[&](size_t elems, size_t esz)->void*{
    off=(off+255)&~(size_t)255; void* p=basep+off; off+=elems*esz; return p;
  };
  const int NINP=18;
  const int insz[NINP]={98304,384,8192,131072,32768,32768,262144,131072,262144,16384,128,65536,256,1572864,131072,256,10240,40};
  float* F[NINP];
  for(int i=0;i<NINP;i++) F[i]=(float*)alloc((size_t)insz[i],4);
  float* XF=F[0];
  float *W1F=F[1],*W2F=F[2],*W2MF=F[3],*W3F=F[4],*W4F=F[5],*W4MF=F[6],*W5F=F[7],*W5MF=F[8],
        *WP1F=F[9],*BP1F=F[10],*WP2F=F[11],*BP2F=F[12],*WL1F=F[13],*WL2F=F[14],*BL2F=F[15],*WL3F=F[16],*BL3F=F[17];
  float* XX  =(float*)alloc((size_t)16*2048,4);
  float* U   =(float*)alloc((size_t)16*64*2048,4);
  float* V   =(float*)alloc((size_t)16*64*2048,4);
  float* XT1 =(float*)alloc((size_t)16*128*2048,4);
  float* XT2 =(float*)alloc((size_t)16*256*256,4);
  float* NF1 =(float*)alloc((size_t)16*128*256,4);
  float* NF2 =(float*)alloc((size_t)16*256*64,4);
  float* X5  =(float*)alloc((size_t)16*256*64,4);
  float* NODE1=(float*)alloc((size_t)16*3*256,4);
  float* NODE2=(float*)alloc((size_t)16*3*64,4);
  float* SCORES=(float*)alloc((size_t)16*2048,4);
  float* PVAL1=(float*)alloc((size_t)16*256,4);
  float* PVAL2=(float*)alloc((size_t)16*64,4);
  float* G   =(float*)alloc((size_t)16*3072,4);
  float* Y1  =(float*)alloc((size_t)16*512,4);
  float* H1  =(float*)alloc((size_t)16*512,4);
  float* Y2  =(float*)alloc((size_t)16*256,4);
  float* H2  =(float*)alloc((size_t)16*256,4);
  float* OUTF=(float*)alloc((size_t)16*40,4);
  u32* GMAX  =(u32*)alloc((size_t)16*3072,4);
  u32* VECENC=(u32*)alloc((size_t)16*256,4);
  int* IDX   =(int*)alloc((size_t)16*2048*20,4);
  int* PIDX1 =(int*)alloc((size_t)16*256,4);
  int* PIDX2 =(int*)alloc((size_t)16*64,4);
  double* STATS=(double*)alloc((size_t)2*1024,8);
  int* FLAG  =(int*)alloc(64,4);
  u16* XTB  =(u16*)alloc((size_t)16*2048*128,2);
  u16* WB2M =(u16*)alloc((size_t)131072,2);
  u16* WB4M =(u16*)alloc((size_t)262144,2);
  u16* WB5M =(u16*)alloc((size_t)262144,2);

  k_detect<<<dim3(1),dim3(TPB),0,stream>>>((const u16*)d_in[1], insz[1], FLAG);
  CvtArgs ca;
  for(int i=0;i<NINP;i++){ ca.s[i]=d_in[i]; ca.d[i]=F[i]; ca.n[i]=insz[i]; }
  k_cvt_all<<<dim3(64,NINP),dim3(TPB),0,stream>>>(ca, FLAG);
  k_castw<<<dim3((131072+TPB-1)/TPB),dim3(TPB),0,stream>>>(W2MF,WB2M,131072);
  k_castw<<<dim3((262144+TPB-1)/TPB),dim3(TPB),0,stream>>>(W4MF,WB4M,262144);
  k_castw<<<dim3((262144+TPB-1)/TPB),dim3(TPB),0,stream>>>(W5MF,WB5M,262144);

  auto knn=[&](const float* X, int ldC, int C, int N, int K){
    k_sqnorm<<<dim3((B*N+TPB-1)/TPB),dim3(TPB),0,stream>>>(X,XX,B,ldC,C,N);
    size_t shm=(size_t)4*N*4;
    if(N==2048 && C==3)       k_knn_fused<32,3>  <<<dim3(8192),dim3(256),shm,stream>>>(X,XX,ldC,K,IDX);
    else if(N==2048)          k_knn_fused<32,64> <<<dim3(8192),dim3(256),shm,stream>>>(X,XX,ldC,K,IDX);
    else if(N==256)           k_knn_fused<4,128> <<<dim3(N/4,B),dim3(256),shm,stream>>>(X,XX,ldC,K,IDX);
    else                      k_knn_fused<1,256> <<<dim3(N/4,B),dim3(256),shm,stream>>>(X,XX,ldC,K,IDX);
  };

  auto graph_conv=[&](const float* X, int ldC, int C, int N, int K, const float* W, int O,
                      float* outBase, int ldCout, int ch_off){
    knn(X,ldC,C,N,K);
    size_t wshm=(size_t)8*C*2*4;
    k_uv_t<<<dim3((N+TPB-1)/TPB,O/8,B),dim3(TPB),wshm,stream>>>(X,ldC,W,U,V,C,N,O);
    hipMemsetAsync(STATS,0,2*(size_t)O*sizeof(double),stream);
    dim3 g((N+TPB-1)/TPB, O/8, B);
    if(K==20)      k_nbr_t<20,8><<<g,dim3(TPB),0,stream>>>(U,V,IDX,outBase,ldCout,ch_off,STATS,O,N);
    else if(K==10) k_nbr_t<10,8><<<g,dim3(TPB),0,stream>>>(U,V,IDX,outBase,ldCout,ch_off,STATS,O,N);
    else           k_nbr_t<5,8> <<<g,dim3(TPB),0,stream>>>(U,V,IDX,outBase,ldCout,ch_off,STATS,O,N);
    double cnt=(double)B*(double)N*(double)K;
    k_bnact<<<dim3((N+TPB-1)/TPB,O,B),dim3(TPB),0,stream>>>(outBase,ldCout,ch_off,STATS,O,N,cnt);
  };

  auto convmax_f32=[&](const float* X,int ldC,const float* W,const float* bias,
                   u32* gmax,int gstride,int g_off,double* stats,int C,int N,int O){
    if(N>=1024) k_convmax<4><<<dim3((N+TPB*4-1)/(TPB*4),O/16,B),dim3(TPB),0,stream>>>(X,ldC,W,bias,gmax,gstride,g_off,stats,C,N,O);
    else        k_convmax<1><<<dim3((N+TPB-1)/TPB,O/16,B),dim3(TPB),0,stream>>>(X,ldC,W,bias,gmax,gstride,g_off,stats,C,N,O);
  };

  auto pool=[&](const float* xyzF,int ldCx,const float* featF,int ldCf,int Cf,int Nin,
                const float* WP,const float* BP,int Op,int Kp,
                float* nodeOut,float* nfOut,int* pidx,float* pval){
    hipMemsetAsync(VECENC,0,(size_t)B*Op*4,stream);
    convmax_f32(featF,ldCf,WP,BP,VECENC,Op,0,(double*)nullptr,Cf,Nin,Op);
    k_scores<<<dim3((Nin+TPB-1)/TPB,B),dim3(TPB),0,stream>>>(featF,ldCf,VECENC,SCORES,Cf,Nin);
    int tsort = (Nin>=1024)? 1024 : TPB;
    k_topk_sort<<<dim3(B),dim3(tsort),(size_t)Nin*8,stream>>>(SCORES,Nin,Kp,pidx,pval);
    k_pgather<<<dim3(((3+Cf)*Kp+TPB-1)/TPB,B),dim3(TPB),0,stream>>>(xyzF,ldCx,featF,ldCf,pidx,pval,nodeOut,nfOut,Cf,Nin,Kp);
  };

  auto gseg=[&](const float* X,int ldC,int C,int N,const u16* WBc,int g_off,double cnt){
    hipMemsetAsync(STATS,0,2*1024*sizeof(double),stream);
    k_xpose_bf<<<dim3((N+31)/32,(C+31)/32,B),dim3(256),0,stream>>>(X,XTB,ldC,C,N);
    dim3 g((N+255)/256, 1024/64, B);
    if(C==128) k_convmax_mfma<4><<<g,dim3(256),0,stream>>>(WBc,XTB,GMAX,3072,g_off,STATS,C,N,1024);
    else       k_convmax_mfma<8><<<g,dim3(256),0,stream>>>(WBc,XTB,GMAX,3072,g_off,STATS,C,N,1024);
    k_gfinal<<<dim3((B*1024+TPB-1)/TPB),dim3(TPB),0,stream>>>(GMAX,3072,g_off,STATS,G,B,1024,cnt);
  };

  graph_conv(XF,3,3,2048,20,W1F,64,XT1,128,0);
  graph_conv(XT1,128,64,2048,20,W2F,64,XT1,128,64);
  hipMemsetAsync(GMAX,0,(size_t)16*3072*4,stream);
  gseg(XT1,128,128,2048,WB2M,0,(double)16*2048);
  pool(XF,3,XT1,128,128,2048,WP1F,BP1F,128,256,NODE1,NF1,PIDX1,PVAL1);
  graph_conv(NF1,128,128,256,10,W3F,128,XT2,256,0);
  graph_conv(XT2,256,128,256,10,W4F,128,XT2,256,128);
  gseg(XT2,256,256,256,WB4M,1024,(double)16*256);
  pool(NODE1,3,XT2,256,256,256,WP2F,BP2F,256,64,NODE2,NF2,PIDX2,PVAL2);
  graph_conv(NF2,256,256,64,5,W5F,256,X5,256,0);
  gseg(X5,256,256,64,WB5M,2048,(double)16*64);
  k_fc_wave<<<dim3((16*512*64+TPB-1)/TPB),dim3(TPB),0,stream>>>(G,WL1F,(const float*)nullptr,Y1,16,3072,512);
  k_bnb<<<dim3((512+TPB-1)/TPB),dim3(TPB),0,stream>>>(Y1,H1,16,512);
  k_fc_wave<<<dim3((16*256*64+TPB-1)/TPB),dim3(TPB),0,stream>>>(H1,WL2F,BL2F,Y2,16,512,256);
  k_bnb<<<dim3((256+TPB-1)/TPB),dim3(TPB),0,stream>>>(Y2,H2,16,256);
  k_fc_wave<<<dim3((16*40*64+TPB-1)/TPB),dim3(TPB),0,stream>>>(H2,WL3F,BL3F,OUTF,16,256,40);
  k_out<<<dim3((16000+TPB-1)/TPB),dim3(TPB),0,stream>>>(OUTF,NODE1,NODE2,(u16*)d_out,FLAG);
}